// Round 16
// baseline (3020.554 us; speedup 1.0000x reference)
//
#include <hip/hip_runtime.h>
#include <hip/hip_bf16.h>
#include <math.h>

// B=32, HID=256, D=64, K=512
// Encoder fp32 (argmin exactness); decoder bf16 MFMA (post-VQ, lenient threshold).

#define OUT_CLOSEST 1572864
#define OUT_QLOSS   1605632

// ---- ws offsets (in floats) ----
#define OFF_BIG   0u
#define OFF_BP    0u
#define OFF_ENC   8388608u
#define OFF_HT1   8388608u
#define OFF_HT2   12582912u
#define OFF_HT3   16777216u
#define OFF_QOT   20971520u
#define OFF_S     33554432u
#define OFF_W2T   41943040u
#define OFF_RW1T  42991616u
#define OFF_RW2T  43581440u
#define OFF_PWT   43646976u
#define OFF_DPWB  43675648u
#define OFF_DRW1B 43683840u
#define OFF_DRW2B 43978752u
#define OFF_TW1B  44273664u
#define OFF_STATS 44797952u
#define OFF_NORM  44798464u
#define OFF_CIDX  44799488u
#define OFF_PART  44832256u
#define OFF_STAT2 44840448u   // also double[4096] for bn partials (time-disjoint)
#define OFF_WB    44873216u   // bf16 65536 (32768 fl): padded L10 weights

typedef __bf16 bf16x8 __attribute__((ext_vector_type(8)));
typedef float f32x4 __attribute__((ext_vector_type(4)));

__device__ __forceinline__ unsigned short f2bf(float f) {
  __hip_bfloat16 h = __float2bfloat16(f);
  return *reinterpret_cast<unsigned short*>(&h);
}
__device__ __forceinline__ float bf2f(unsigned short u) {
  return __uint_as_float((unsigned)u << 16);
}

// ---------------- one-shot prep: all weight permutes + codebook norms ----------------
__global__ __launch_bounds__(256) void prep_all(
    const float* __restrict__ e_w2, float* __restrict__ W2T,
    const float* __restrict__ e_rw1, float* __restrict__ RW1T,
    const float* __restrict__ e_rw2, float* __restrict__ RW2T,
    const float* __restrict__ e_pw, float* __restrict__ PWT,
    const float* __restrict__ d_tw2, __hip_bfloat16* __restrict__ WB,
    const float* __restrict__ d_pw, __hip_bfloat16* __restrict__ DPWB,
    const float* __restrict__ d_rw1, __hip_bfloat16* __restrict__ DRW1B,
    const float* __restrict__ d_rw2, __hip_bfloat16* __restrict__ DRW2B,
    const float* __restrict__ d_tw1, __hip_bfloat16* __restrict__ TW1B,
    const float* __restrict__ emb, double* __restrict__ NORM) {
  const int bid = blockIdx.x, tid = threadIdx.x;
  if (bid < 4096) {
    int i = bid * 256 + tid;
    int co = i & 255; int r = i >> 8; int ci = r & 255; int t = r >> 8;
    W2T[i] = e_w2[((size_t)co * 256 + ci) * 16 + t];
  } else if (bid < 6400) {
    int i = (bid - 4096) * 256 + tid;
    if (i < 589824) {
      int co = i % 256; int r = i / 256; int ci = r % 256; int t = r / 256;
      RW1T[i] = e_rw1[((size_t)co * 256 + ci) * 9 + t];
    }
  } else if (bid < 6656) {
    int i = (bid - 6400) * 256 + tid;
    int co = i & 255; int ci = i >> 8;
    RW2T[i] = e_rw2[(size_t)co * 256 + ci];
  } else if (bid < 6720) {
    int i = (bid - 6656) * 256 + tid;
    int co = i & 63; int ci = i >> 6;
    PWT[i] = e_pw[(size_t)co * 256 + ci];
  } else if (bid < 6976) {
    int i = (bid - 6720) * 256 + tid;
    int e = i & 7; int ln = (i >> 3) & 15; int ciq = (i >> 7) & 31; int t = i >> 12;
    int ci = ciq * 8 + e;
    float v = (ln < 3) ? d_tw2[((size_t)ci * 3 + ln) * 16 + t] : 0.f;
    WB[i] = __float2bfloat16(v);
  } else if (bid < 7040) {
    int i = (bid - 6976) * 256 + tid;
    int ci = i & 63; int co = i >> 6;
    DPWB[i] = __float2bfloat16(d_pw[(size_t)co * 64 + ci]);
  } else if (bid < 9344) {
    int i = (bid - 7040) * 256 + tid;
    if (i < 589824) {
      int ci = i % 256; int r = i / 256; int co = r % 256; int t = r / 256;
      DRW1B[i] = __float2bfloat16(d_rw1[((size_t)co * 256 + ci) * 9 + t]);
    }
  } else if (bid < 11648) {
    int i = (bid - 9344) * 256 + tid;
    if (i < 589824) {
      int ci = i % 256; int r = i / 256; int co = r % 256; int t = r / 256;
      DRW2B[i] = __float2bfloat16(d_rw2[((size_t)co * 256 + ci) * 9 + t]);
    }
  } else if (bid < 15744) {
    int i = (bid - 11648) * 256 + tid;
    int ci = i & 255; int r = i >> 8; int co = r & 255; int t = r >> 8;
    TW1B[i] = __float2bfloat16(d_tw1[((size_t)ci * 256 + co) * 16 + t]);
  } else {
    int k = (bid - 15744) * 256 + tid;
    if (k < 512) {
      double s = 0.0;
      for (int d = 0; d < 64; ++d) { double e = emb[(k << 6) + d]; s += e * e; }
      NORM[k] = s;
    }
  }
}

// ---------------- L1 conv: strip-tiled, co-split (4 blocks/CU) ----------------
__global__ __launch_bounds__(256) void conv1_w(const float* __restrict__ x, const float* __restrict__ w,
                                               const float* __restrict__ bias, float* __restrict__ out) {
  __shared__ float ws[6144];
  __shared__ float xs[3][10][132];
  const int tid = threadIdx.x;
  const int s = blockIdx.x, b = blockIdx.y, ch = blockIdx.z;
  for (int i = tid; i < 1536; i += 256)
    *(float4*)&ws[i * 4] = *(const float4*)&w[ch * 6144 + i * 4];
  for (int i = tid; i < 3 * 10 * 130; i += 256) {
    int col = i % 130; int r2 = i / 130; int lr = r2 % 10; int ci = r2 / 10;
    int ih = 8 * s - 1 + lr; int iw = col - 1;
    float v = 0.f;
    if ((unsigned)ih < 128u && (unsigned)iw < 128u)
      v = x[((size_t)(b * 3 + ci) << 14) + (ih << 7) + iw];
    xs[ci][lr][col] = v;
  }
  __syncthreads();
  const int ohl = tid >> 6, ow = tid & 63;
  const int oh = (s << 2) + ohl;
  float xr[48];
#pragma unroll
  for (int ci = 0; ci < 3; ++ci)
#pragma unroll
    for (int kh = 0; kh < 4; ++kh)
#pragma unroll
      for (int kw = 0; kw < 4; ++kw)
        xr[(ci * 4 + kh) * 4 + kw] = xs[ci][2 * ohl + kh][2 * ow + kw];
  float* op = out + (((size_t)b * 256) << 12) + (oh << 6) + ow;
  for (int co = 0; co < 128; ++co) {
    float acc = bias[ch * 128 + co];
    const float* wp = &ws[co * 48];
#pragma unroll
    for (int k = 0; k < 48; k += 4) {
      float4 wv = *(const float4*)&wp[k];
      acc = fmaf(xr[k], wv.x, acc);
      acc = fmaf(xr[k + 1], wv.y, acc);
      acc = fmaf(xr[k + 2], wv.z, acc);
      acc = fmaf(xr[k + 3], wv.w, acc);
    }
    op[(size_t)(ch * 128 + co) << 12] = acc;
  }
}

// ---------------- BN stats: two-stage, deterministic ----------------
__global__ __launch_bounds__(256) void bn_stats_p(const float* __restrict__ in, double* __restrict__ part,
                                                  int log2HW, int Bn) {
  int c = blockIdx.x, g = blockIdx.y;
  int tid = threadIdx.x;
  int HW = 1 << log2HW;
  int cnt = Bn << log2HW;
  int seg = cnt >> 3;
  double s = 0.0, s2 = 0.0;
  for (int i = g * seg + tid; i < (g + 1) * seg; i += 256) {
    int b = i >> log2HW, p = i & (HW - 1);
    float v = in[((size_t)(b * 256 + c) << log2HW) + p];
    s += v; s2 += (double)v * v;
  }
  __shared__ double r1[256], r2[256];
  r1[tid] = s; r2[tid] = s2;
  __syncthreads();
  for (int st = 128; st > 0; st >>= 1) {
    if (tid < st) { r1[tid] += r1[tid + st]; r2[tid] += r2[tid + st]; }
    __syncthreads();
  }
  if (tid == 0) {
    part[(c << 3) + g] = r1[0];
    part[2048 + (c << 3) + g] = r2[0];
  }
}
__global__ __launch_bounds__(256) void bn_stats_f(const double* __restrict__ part, float* __restrict__ stats,
                                                  int cnt) {
  int c = threadIdx.x;
  double s = 0.0, s2 = 0.0;
  for (int g = 0; g < 8; ++g) { s += part[(c << 3) + g]; s2 += part[2048 + (c << 3) + g]; }
  double m = s / cnt;
  double var = s2 / cnt - m * m;
  stats[c] = (float)m;
  stats[256 + c] = (float)(1.0 / sqrt(var + 1e-5));
}

__global__ __launch_bounds__(256) void bn_apply(const float4* __restrict__ in, const float4* __restrict__ res,
                                                float4* __restrict__ out, const float* __restrict__ stats,
                                                const float* __restrict__ g, const float* __restrict__ be,
                                                int log2HW, int n4) {
  int i = blockIdx.x * 256 + threadIdx.x;
  if (i >= n4) return;
  int c = (i >> (log2HW - 2)) & 255;
  float sc = stats[256 + c] * g[c];
  float sh = be[c] - stats[c] * sc;
  float4 v = in[i];
  float4 o;
  o.x = fmaxf(fmaf(v.x, sc, sh), 0.f);
  o.y = fmaxf(fmaf(v.y, sc, sh), 0.f);
  o.z = fmaxf(fmaf(v.z, sc, sh), 0.f);
  o.w = fmaxf(fmaf(v.w, sc, sh), 0.f);
  if (res) { float4 r = res[i]; o.x += r.x; o.y += r.y; o.z += r.z; o.w += r.w; }
  out[i] = o;
}

// BN+ReLU+res for decoder 32x32 layers
__global__ __launch_bounds__(256) void bn_apply_td(const float* __restrict__ in, const float* __restrict__ res,
                                                   float* __restrict__ out_f, __hip_bfloat16* __restrict__ out_bt,
                                                   const float* __restrict__ stats, const float* __restrict__ g,
                                                   const float* __restrict__ be) {
  int j = blockIdx.x * 256 + threadIdx.x;
  int sp = j & 1023, cg = (j >> 10) & 31, b = j >> 15;
  unsigned short us[8];
#pragma unroll
  for (int q = 0; q < 8; ++q) {
    int c = cg * 8 + q;
    float sc = stats[256 + c] * g[c];
    float sh = be[c] - stats[c] * sc;
    size_t idx = ((size_t)(b * 256 + c) << 10) + sp;
    float y = fmaxf(fmaf(in[idx], sc, sh), 0.f) + res[idx];
    if (out_f) out_f[idx] = y;
    us[q] = f2bf(y);
  }
  ushort4* op = (ushort4*)(out_bt + (((size_t)(b << 10) + sp) << 8) + cg * 8);
  op[0] = make_ushort4(us[0], us[1], us[2], us[3]);
  op[1] = make_ushort4(us[4], us[5], us[6], us[7]);
}

// fp32 NCHW (32,256,1024) -> bf16 (b, sp, c)
__global__ __launch_bounds__(256) void fp32_to_bt(const float* __restrict__ in, __hip_bfloat16* __restrict__ out) {
  int j = blockIdx.x * 256 + threadIdx.x;
  int sp = j & 1023, cg = (j >> 10) & 31, b = j >> 15;
  unsigned short us[8];
#pragma unroll
  for (int q = 0; q < 8; ++q) {
    int c = cg * 8 + q;
    us[q] = f2bf(in[((size_t)(b * 256 + c) << 10) + sp]);
  }
  ushort4* op = (ushort4*)(out + (((size_t)(b << 10) + sp) << 8) + cg * 8);
  op[0] = make_ushort4(us[0], us[1], us[2], us[3]);
  op[1] = make_ushort4(us[4], us[5], us[6], us[7]);
}

// ---------------- MFMA conv (decoder 1x1, CI=64) ----------------
template<int CI, int KH, int KW, int PAD>
__global__ __launch_bounds__(256) void mconv(const __hip_bfloat16* __restrict__ act,
                                             const __hip_bfloat16* __restrict__ wt,
                                             const float* __restrict__ bias,
                                             float* __restrict__ out, int CO) {
  const int tid = threadIdx.x;
  const int lane = tid & 63, wv = tid >> 6;
  const int ln = lane & 15, kg = lane >> 4;
  const int b = blockIdx.z;
  const int co_base = blockIdx.y << 6;
  const int sp_base = blockIdx.x << 6;
  const int co_n = co_base + wv * 16 + ln;
  int oh[4], ow[4];
#pragma unroll
  for (int mf = 0; mf < 4; ++mf) {
    int s = sp_base + mf * 16 + ln;
    oh[mf] = s >> 5; ow[mf] = s & 31;
  }
  f32x4 acc[4] = {{0,0,0,0},{0,0,0,0},{0,0,0,0},{0,0,0,0}};
  const size_t actb = (size_t)b * 1024 * CI;
  const int kg8 = kg * 8;
  for (int kh = 0; kh < KH; ++kh)
    for (int kw = 0; kw < KW; ++kw) {
      const int t = kh * KW + kw;
      const __hip_bfloat16* bp = wt + ((size_t)t * CO + co_n) * CI + kg8;
      const __hip_bfloat16* ap[4]; bool val[4];
#pragma unroll
      for (int mf = 0; mf < 4; ++mf) {
        int ih = oh[mf] + kh - PAD, iw = ow[mf] + kw - PAD;
        val[mf] = ((unsigned)ih < 32u) && ((unsigned)iw < 32u);
        ap[mf] = val[mf] ? (act + actb + (size_t)((ih << 5) + iw) * CI + kg8) : (act + actb + kg8);
      }
#pragma unroll
      for (int ci0 = 0; ci0 < CI; ci0 += 32) {
        bf16x8 bf = *(const bf16x8*)(bp + ci0);
        bf16x8 af[4];
#pragma unroll
        for (int mf = 0; mf < 4; ++mf) {
          bf16x8 z = {};
          bf16x8 tv = *(const bf16x8*)(ap[mf] + ci0);
          af[mf] = val[mf] ? tv : z;
        }
#pragma unroll
        for (int mf = 0; mf < 4; ++mf)
          acc[mf] = __builtin_amdgcn_mfma_f32_16x16x32_bf16(af[mf], bf, acc[mf], 0, 0, 0);
      }
    }
  float bv = bias[co_n];
#pragma unroll
  for (int mf = 0; mf < 4; ++mf) {
    int sp_r = sp_base + mf * 16 + kg * 4;
    float4 r = make_float4(acc[mf][0] + bv, acc[mf][1] + bv, acc[mf][2] + bv, acc[mf][3] + bv);
    *(float4*)&out[((size_t)(b * CO + co_n) << 10) + sp_r] = r;
  }
}

// ---------------- MFMA 3x3 conv with LDS-staged act (CI=256, CO=256, pad 1) ----------------
__global__ __launch_bounds__(256, 4) void mconv_s(const __hip_bfloat16* __restrict__ act,
                                                  const __hip_bfloat16* __restrict__ wt,
                                                  const float* __restrict__ bias,
                                                  float* __restrict__ out) {
  __shared__ __hip_bfloat16 As[4 * 34 * 136];   // 36 KB
  const int tid = threadIdx.x;
  const int lane = tid & 63, wv = tid >> 6;
  const int ln = lane & 15, kg = lane >> 4;
  const int b = blockIdx.z;
  const int co_base = blockIdx.y << 6;
  const int sp_base = blockIdx.x << 6;
  const int co_n = co_base + wv * 16 + ln;
  const int r_first = (sp_base >> 5) - 1;
  const size_t actb = (size_t)b << 18;
  const int kg8 = kg * 8;

  f32x4 acc[4] = {{0,0,0,0},{0,0,0,0},{0,0,0,0},{0,0,0,0}};

  int lr0[4], lc0[4];
#pragma unroll
  for (int mf = 0; mf < 4; ++mf) {
    int s = mf * 16 + ln;
    lr0[mf] = s >> 5;
    lc0[mf] = s & 31;
  }

  for (int cih = 0; cih < 2; ++cih) {
    __syncthreads();
    for (int sIdx = tid; sIdx < 2176; sIdx += 256) {
      int v8 = sIdx & 15;
      int rc = sIdx >> 4;
      int col = rc % 34;
      int row = rc / 34;
      int ih = r_first + row;
      int iw = col - 1;
      uint4 val = make_uint4(0, 0, 0, 0);
      if ((unsigned)ih < 32u && (unsigned)iw < 32u)
        val = *(const uint4*)(act + actb + ((size_t)((ih << 5) + iw) << 8) + cih * 128 + v8 * 8);
      *(uint4*)(&As[rc * 136 + v8 * 8]) = val;
    }
    __syncthreads();
#pragma unroll
    for (int kh = 0; kh < 3; ++kh)
#pragma unroll
      for (int kw = 0; kw < 3; ++kw) {
        const int t = kh * 3 + kw;
        const __hip_bfloat16* bp = wt + ((size_t)t * 256 + co_n) * 256 + cih * 128 + kg8;
#pragma unroll
        for (int c32 = 0; c32 < 4; ++c32) {
          bf16x8 bf = *(const bf16x8*)(bp + (c32 << 5));
#pragma unroll
          for (int mf = 0; mf < 4; ++mf) {
            int lrow = lr0[mf] + kh;
            int lcol = lc0[mf] + kw;
            bf16x8 af = *(const bf16x8*)(&As[(lrow * 34 + lcol) * 136 + (c32 << 5) + kg8]);
            acc[mf] = __builtin_amdgcn_mfma_f32_16x16x32_bf16(af, bf, acc[mf], 0, 0, 0);
          }
        }
      }
  }
  float bv = bias[co_n];
#pragma unroll
  for (int mf = 0; mf < 4; ++mf) {
    int sp_r = sp_base + mf * 16 + kg * 4;
    float4 r = make_float4(acc[mf][0] + bv, acc[mf][1] + bv, acc[mf][2] + bv, acc[mf][3] + bv);
    *(float4*)&out[((size_t)(b * 256 + co_n) << 10) + sp_r] = r;
  }
}

// ---------------- MFMA deconv L9, PHASE-FUSED + LDS-staged act ----------------
__global__ __launch_bounds__(256) void mdeconv_s(const __hip_bfloat16* __restrict__ act,
                                                 const __hip_bfloat16* __restrict__ wt,
                                                 const float* __restrict__ bias,
                                                 __hip_bfloat16* __restrict__ out) {
  __shared__ __hip_bfloat16 As[4 * 34 * 136];   // 36 KB
  const int tid = threadIdx.x;
  const int lane = tid & 63, wv = tid >> 6;
  const int ln = lane & 15, kg = lane >> 4;
  const int b = blockIdx.z;
  const int co_base = blockIdx.y << 6;
  const int sp_base = blockIdx.x << 6;
  const int co_a = co_base + wv * 16 + ln;
  const int r_first = (sp_base >> 5) - 1;
  const size_t actb = (size_t)b << 18;
  const int kg8 = kg * 8;

  int lr0[4], lc0[4];
#pragma unroll
  for (int mf = 0; mf < 4; ++mf) {
    int s = mf * 16 + ln;
    lr0[mf] = s >> 5;
    lc0[mf] = s & 31;
  }

  f32x4 acc[16];
#pragma unroll
  for (int q = 0; q < 16; ++q) acc[q] = (f32x4){0, 0, 0, 0};

  const int nmem[3]     = {1, 2, 1};
  const int khm[3][2]   = {{3, 0}, {1, 2}, {0, 0}};
  const int phm[3][2]   = {{0, 0}, {0, 1}, {1, 0}};

  for (int cih = 0; cih < 2; ++cih) {
    __syncthreads();
    for (int sIdx = tid; sIdx < 2176; sIdx += 256) {
      int v8 = sIdx & 15;
      int rc = sIdx >> 4;
      int col = rc % 34;
      int row = rc / 34;
      int ih = r_first + row;
      int iw = col - 1;
      uint4 val = make_uint4(0, 0, 0, 0);
      if ((unsigned)ih < 32u && (unsigned)iw < 32u)
        val = *(const uint4*)(act + actb + ((size_t)((ih << 5) + iw) << 8) + cih * 128 + v8 * 8);
      *(uint4*)(&As[rc * 136 + v8 * 8]) = val;
    }
    __syncthreads();
#pragma unroll
    for (int di = 0; di < 3; ++di) {
#pragma unroll
      for (int dj = 0; dj < 3; ++dj) {
#pragma unroll
        for (int u = 0; u < 2; ++u) {
          if (u < nmem[di]) {
#pragma unroll
            for (int v = 0; v < 2; ++v) {
              if (v < nmem[dj]) {
                const int t = khm[di][u] * 4 + khm[dj][v];
                const int pidx = (phm[di][u] * 2 + phm[dj][v]) << 2;
                const __hip_bfloat16* bp = wt + ((size_t)t * 256 + co_a) * 256 + cih * 128 + kg8;
#pragma unroll
                for (int c32 = 0; c32 < 4; ++c32) {
                  bf16x8 af = *(const bf16x8*)(bp + (c32 << 5));
#pragma unroll
                  for (int mf = 0; mf < 4; ++mf) {
                    int lrow = lr0[mf] + di;
                    int lcol = lc0[mf] + dj;
                    bf16x8 bfr = *(const bf16x8*)(&As[(lrow * 34 + lcol) * 136 + (c32 << 5) + kg8]);
                    acc[pidx + mf] = __builtin_amdgcn_mfma_f32_16x16x32_bf16(af, bfr, acc[pidx + mf], 0, 0, 0);
                  }
                }
              }
            }
          }
        }
      }
    }
  }
  const int co_r = co_base + wv * 16 + kg * 4;
  float b0 = bias[co_r], b1 = bias[co_r + 1], b2 = bias[co_r + 2], b3 = bias[co_r + 3];
#pragma unroll
  for (int ph = 0; ph < 2; ++ph)
#pragma unroll
    for (int pw = 0; pw < 2; ++pw) {
      const int pidx = (ph * 2 + pw) << 2;
#pragma unroll
      for (int mf = 0; mf < 4; ++mf) {
        int s = sp_base + mf * 16 + ln;
        int a = s >> 5, c = s & 31;
        size_t obase = (((size_t)(b << 12)) + (((a << 1) + ph) << 6) + (c << 1) + pw) << 8;
        f32x4 av = acc[pidx + mf];
        ushort4 u = make_ushort4(f2bf(av[0] + b0), f2bf(av[1] + b1),
                                 f2bf(av[2] + b2), f2bf(av[3] + b3));
        *(ushort4*)(out + obase + co_r) = u;
      }
    }
}

// ---------------- BN stats over bf16 transposed (b, 4096, 256) ----------------
__global__ __launch_bounds__(256) void bnbt_stage1(const __hip_bfloat16* __restrict__ in, float* __restrict__ part) {
  int t = threadIdx.x, blk = blockIdx.x;
  float s[8] = {0,0,0,0,0,0,0,0}, s2[8] = {0,0,0,0,0,0,0,0};
  size_t base = ((size_t)blk * 256 + t) * 8;
  const size_t stride = 64 * 256 * 8;
  for (int it = 0; it < 256; ++it) {
    ushort4 u0 = *(const ushort4*)(in + base);
    ushort4 u1 = *(const ushort4*)(in + base + 4);
    float v[8] = {bf2f(u0.x), bf2f(u0.y), bf2f(u0.z), bf2f(u0.w),
                  bf2f(u1.x), bf2f(u1.y), bf2f(u1.z), bf2f(u1.w)};
#pragma unroll
    for (int q = 0; q < 8; ++q) { s[q] += v[q]; s2[q] += v[q] * v[q]; }
    base += stride;
  }
  __shared__ float ls[256][8], ls2[256][8];
#pragma unroll
  for (int q = 0; q < 8; ++q) { ls[t][q] = s[q]; ls2[t][q] = s2[q]; }
  __syncthreads();
  if (t < 32) {
#pragma unroll
    for (int q = 0; q < 8; ++q) {
      float a = 0.f, a2 = 0.f;
      for (int r = 0; r < 8; ++r) { a += ls[t + 32 * r][q]; a2 += ls2[t + 32 * r][q]; }
      part[blk * 256 + t * 8 + q] = a;
      part[16384 + blk * 256 + t * 8 + q] = a2;
    }
  }
}

__global__ __launch_bounds__(256) void bnbt_stage2(const float* __restrict__ part, float* __restrict__ stats) {
  int c = threadIdx.x;
  double s = 0.0, s2 = 0.0;
  for (int q = 0; q < 64; ++q) { s += part[q * 256 + c]; s2 += part[16384 + q * 256 + c]; }
  double m = s / 131072.0;
  double var = s2 / 131072.0 - m * m;
  stats[c] = (float)m;
  stats[256 + c] = (float)(1.0 / sqrt(var + 1e-5));
}

__global__ __launch_bounds__(256) void bn_apply_bt(__hip_bfloat16* __restrict__ io, const float* __restrict__ stats,
                                                   const float* __restrict__ g, const float* __restrict__ be) {
  int i = blockIdx.x * 256 + threadIdx.x;
  size_t off = (size_t)i * 8;
  int c0 = (i & 31) * 8;
  ushort4 u0 = *(const ushort4*)(io + off);
  ushort4 u1 = *(const ushort4*)(io + off + 4);
  float v[8] = {bf2f(u0.x), bf2f(u0.y), bf2f(u0.z), bf2f(u0.w),
                bf2f(u1.x), bf2f(u1.y), bf2f(u1.z), bf2f(u1.w)};
  unsigned short us[8];
#pragma unroll
  for (int q = 0; q < 8; ++q) {
    int c = c0 + q;
    float sc = stats[256 + c] * g[c];
    float sh = be[c] - stats[c] * sc;
    us[q] = f2bf(fmaxf(fmaf(v[q], sc, sh), 0.f));
  }
  *(ushort4*)(io + off) = make_ushort4(us[0], us[1], us[2], us[3]);
  *(ushort4*)(io + off + 4) = make_ushort4(us[4], us[5], us[6], us[7]);
}

// ---------------- encoder conv: 128co x 64sp tile, 8co x 4sp per thread ----------------
template<int STRIDE, int KK>
__global__ __launch_bounds__(256, 4) void conv_b64(
    const float* __restrict__ in, const float* __restrict__ wt,
    const float* __restrict__ bias, float* __restrict__ out,
    int CI, int CO, int Hin, int Win, int pad) {
  __shared__ float Xs[2][16][64];
  __shared__ float Ws[2][16][128];
  const int tid = threadIdx.x;
  const int cb = tid & 15, sb = tid >> 4;
  const int sx = tid >> 4;
  const int cx = (tid & 15) << 2;
  const int tw = tid >> 5;
  const int ww = (tid & 31) << 2;
  const int b = blockIdx.z;
  const int co0 = blockIdx.y << 7;
  const int sp0 = blockIdx.x << 6;
  const int HWin = Hin * Win;
  const int nst = KK * KK * 16;

  int oh_s[4], ow_s[4];
#pragma unroll
  for (int q = 0; q < 4; ++q) {
    int s = sp0 + cx + q;
    oh_s[q] = s >> 5; ow_s[q] = s & 31;
  }

  float acc[8][4];
#pragma unroll
  for (int i = 0; i < 8; ++i)
#pragma unroll
    for (int j = 0; j < 4; ++j) acc[i][j] = 0.f;

  float pv[4];
  float4 pw0, pw1;

  auto gather = [&](int st) {
    int t = st >> 4;
    int ci0 = (st & 15) << 4;
    int kh = t / KK, kw = t - kh * KK;
    const float* ib = in + (size_t)(b * CI + ci0 + sx) * HWin;
#pragma unroll
    for (int q = 0; q < 4; ++q) {
      int ih = oh_s[q] * STRIDE + kh - pad;
      int iw = ow_s[q] * STRIDE + kw - pad;
      bool ok = ((unsigned)ih < (unsigned)Hin) && ((unsigned)iw < (unsigned)Win);
      pv[q] = ok ? ib[ih * Win + iw] : 0.f;
    }
    const float* wb = wt + ((size_t)t * CI + ci0 + tw) * CO + co0 + ww;
    pw0 = *(const float4*)wb;
    pw1 = *(const float4*)(wb + (size_t)8 * CO);
  };

  gather(0);
  *(float4*)&Xs[0][sx][cx]     = make_float4(pv[0], pv[1], pv[2], pv[3]);
  *(float4*)&Ws[0][tw][ww]     = pw0;
  *(float4*)&Ws[0][tw + 8][ww] = pw1;
  __syncthreads();

  for (int st = 0; st < nst; ++st) {
    const int cur = st & 1;
    const bool more = (st + 1 < nst);
    if (more) gather(st + 1);
    const float (*Xc)[64]  = Xs[cur];
    const float (*Wc)[128] = Ws[cur];
#pragma unroll 4
    for (int ci = 0; ci < 16; ++ci) {
      float4 w0 = *(const float4*)&Wc[ci][cb << 2];
      float4 w1 = *(const float4*)&Wc[ci][64 + (cb << 2)];
      float4 xv = *(const float4*)&Xc[ci][sb << 2];
#define FMA_ROW(I, WC) \
      acc[I][0] = fmaf(WC, xv.x, acc[I][0]); \
      acc[I][1] = fmaf(WC, xv.y, acc[I][1]); \
      acc[I][2] = fmaf(WC, xv.z, acc[I][2]); \
      acc[I][3] = fmaf(WC, xv.w, acc[I][3]);
      FMA_ROW(0, w0.x) FMA_ROW(1, w0.y) FMA_ROW(2, w0.z) FMA_ROW(3, w0.w)
      FMA_ROW(4, w1.x) FMA_ROW(5, w1.y) FMA_ROW(6, w1.z) FMA_ROW(7, w1.w)
#undef FMA_ROW
    }
    if (more) {
      const int nxt = cur ^ 1;
      *(float4*)&Xs[nxt][sx][cx]     = make_float4(pv[0], pv[1], pv[2], pv[3]);
      *(float4*)&Ws[nxt][tw][ww]     = pw0;
      *(float4*)&Ws[nxt][tw + 8][ww] = pw1;
      __syncthreads();
    }
  }

#pragma unroll
  for (int i = 0; i < 8; ++i) {
    int co = co0 + ((i < 4) ? (cb << 2) + i : 64 + (cb << 2) + (i - 4));
    float bv = bias[co];
    *(float4*)&out[((size_t)(b * CO + co) << 10) + sp0 + (sb << 2)] =
        make_float4(acc[i][0] + bv, acc[i][1] + bv, acc[i][2] + bv, acc[i][3] + bv);
  }
}

// ---------------- encoder tiled conv (fp32, for L5 CO=64) ----------------
__device__ __forceinline__ void tile_fma(const float* Ws_, const float* Xs_, int co4, int sp4,
                                         float acc[4][4]) {
#pragma unroll
  for (int ci = 0; ci < 16; ++ci) {
    float4 wv = *(const float4*)(Ws_ + (ci << 6) + co4);
    float4 xv = *(const float4*)(Xs_ + (ci << 6) + sp4);
    acc[0][0] = fmaf(xv.x, wv.x, acc[0][0]);
    acc[0][1] = fmaf(xv.x, wv.y, acc[0][1]);
    acc[0][2] = fmaf(xv.x, wv.z, acc[0][2]);
    acc[0][3] = fmaf(xv.x, wv.w, acc[0][3]);
    acc[1][0] = fmaf(xv.y, wv.x, acc[1][0]);
    acc[1][1] = fmaf(xv.y, wv.y, acc[1][1]);
    acc[1][2] = fmaf(xv.y, wv.z, acc[1][2]);
    acc[1][3] = fmaf(xv.y, wv.w, acc[1][3]);
    acc[2][0] = fmaf(xv.z, wv.x, acc[2][0]);
    acc[2][1] = fmaf(xv.z, wv.y, acc[2][1]);
    acc[2][2] = fmaf(xv.z, wv.z, acc[2][2]);
    acc[2][3] = fmaf(xv.z, wv.w, acc[2][3]);
    acc[3][0] = fmaf(xv.w, wv.x, acc[3][0]);
    acc[3][1] = fmaf(xv.w, wv.y, acc[3][1]);
    acc[3][2] = fmaf(xv.w, wv.z, acc[3][2]);
    acc[3][3] = fmaf(xv.w, wv.w, acc[3][3]);
  }
}

__global__ __launch_bounds__(256) void conv_tiled(
    const float* __restrict__ in, const float* __restrict__ wt,
    const float* __restrict__ bias, float* __restrict__ out,
    int CI, int CO, int Hin, int Win, int Hout, int Wout,
    int KH, int KW, int stride, int pad) {
  __shared__ float Xs[16 * 64];
  __shared__ float Ws[16 * 64];
  const int tid = threadIdx.x;
  const int b = blockIdx.z;
  const int co_base = blockIdx.y << 6;
  const int sp_base = blockIdx.x << 6;
  const int lo = tid & 15, hi = tid >> 4;
  const int co4 = lo << 2, sp4 = hi << 2;
  const int HWin = Hin * Win, HWout = Hout * Wout;

  int oh0[4], ow0[4];
#pragma unroll
  for (int j = 0; j < 4; ++j) {
    int s = sp_base + (lo << 2) + j;
    oh0[j] = s / Wout; ow0[j] = s - oh0[j] * Wout;
  }
  float acc[4][4] = {{0.f,0.f,0.f,0.f},{0.f,0.f,0.f,0.f},{0.f,0.f,0.f,0.f},{0.f,0.f,0.f,0.f}};

  for (int kh = 0; kh < KH; ++kh)
    for (int kw = 0; kw < KW; ++kw) {
      const int t = kh * KW + kw;
      for (int ci0 = 0; ci0 < CI; ci0 += 16) {
        const float* ib = in + (size_t)(b * CI + ci0 + hi) * HWin;
        float v[4];
#pragma unroll
        for (int j = 0; j < 4; ++j) {
          int ih = oh0[j] * stride + kh - pad;
          int iw = ow0[j] * stride + kw - pad;
          v[j] = 0.f;
          if ((unsigned)ih < (unsigned)Hin && (unsigned)iw < (unsigned)Win)
            v[j] = ib[ih * Win + iw];
        }
        *(float4*)&Xs[(hi << 6) + (lo << 2)] = make_float4(v[0], v[1], v[2], v[3]);
        *(float4*)&Ws[(hi << 6) + (lo << 2)] =
            *(const float4*)&wt[((size_t)t * CI + ci0 + hi) * CO + co_base + (lo << 2)];
        __syncthreads();
        tile_fma(Ws, Xs, co4, sp4, acc);
        __syncthreads();
      }
    }
#pragma unroll
  for (int i = 0; i < 4; ++i) {
    int co = co_base + co4 + i;
    float bv = bias[co];
    float4 r = make_float4(acc[0][i] + bv, acc[1][i] + bv, acc[2][i] + bv, acc[3][i] + bv);
    *(float4*)&out[(size_t)(b * CO + co) * HWout + sp_base + sp4] = r;
  }
}

// ---------------- L10 via MFMA ----------------
__global__ __launch_bounds__(256) void deconv_mfma(const __hip_bfloat16* __restrict__ xt,
                                                   const __hip_bfloat16* __restrict__ wb,
                                                   const float* __restrict__ bias, float* __restrict__ out) {
  const int tid = threadIdx.x;
  const int wv = tid >> 6, lane = tid & 63;
  const int ln = lane & 15, kg = lane >> 4;
  const int posb = blockIdx.x * 256 + wv * 64;
  const int sect = posb >> 12;
  const int b = sect >> 2, ph = (sect >> 1) & 1, pw = sect & 1;
  const int a = (posb >> 6) & 63;
  int khs[2], dhs[2], kws[2], dws[2];
  if (ph == 0) { khs[0]=1; dhs[0]=0; khs[1]=3; dhs[1]=-1; }
  else         { khs[0]=0; dhs[0]=1; khs[1]=2; dhs[1]=0; }
  if (pw == 0) { kws[0]=1; dws[0]=0; kws[1]=3; dws[1]=-1; }
  else         { kws[0]=0; dws[0]=1; kws[1]=2; dws[1]=0; }
  f32x4 acc[4] = {{0,0,0,0},{0,0,0,0},{0,0,0,0},{0,0,0,0}};
  const size_t actb = (size_t)b << 12;
#pragma unroll
  for (int ti = 0; ti < 2; ++ti) {
    int ih = a + dhs[ti];
    if ((unsigned)ih >= 64u) continue;
#pragma unroll
    for (int tj = 0; tj < 2; ++tj) {
      const int t = khs[ti] * 4 + kws[tj];
      const int dw = dws[tj];
      const __hip_bfloat16* xrow = xt + ((actb + (ih << 6)) << 8);
#pragma unroll
      for (int c32 = 0; c32 < 8; ++c32) {
        bf16x8 bf = *(const bf16x8*)(wb + ((((size_t)t * 32 + (c32 << 2) + kg) * 16 + ln) << 3));
#pragma unroll
        for (int mf = 0; mf < 4; ++mf) {
          int c = (mf << 4) + ln;
          int iw = c + dw;
          bf16x8 av = {};
          if ((unsigned)iw < 64u)
            av = *(const bf16x8*)(xrow + ((size_t)iw << 8) + (c32 << 5) + (kg << 3));
          acc[mf] = __builtin_amdgcn_mfma_f32_16x16x32_bf16(av, bf, acc[mf], 0, 0, 0);
        }
      }
    }
  }
  if (ln < 3) {
    float bv = bias[ln];
    int oh = 2 * a + ph;
    size_t ob = ((size_t)(b * 3 + ln) << 14) + (oh << 7) + pw;
#pragma unroll
    for (int mf = 0; mf < 4; ++mf)
#pragma unroll
      for (int r = 0; r < 4; ++r) {
        int c = (mf << 4) + (kg << 2) + r;
        out[ob + (c << 1)] = 1.f / (1.f + __expf(-(acc[mf][r] + bv)));
      }
  }
}

// ---------------- VQ: fp32 pass + exact-f64 fallback for near-ties ----------------
__global__ __launch_bounds__(128) void vq_argmin(const float* __restrict__ enc, const float* __restrict__ emb,
                                                 const double* __restrict__ norms, int* __restrict__ cidx,
                                                 float* __restrict__ closest_out) {
  __shared__ float se[128 * 64];
  int tid = threadIdx.x;
  int r = blockIdx.x * 128 + tid;
  float ef[64];
  const float4* ep = (const float4*)(enc + ((size_t)r << 6));
#pragma unroll
  for (int q = 0; q < 16; ++q) {
    float4 v = ep[q];
    ef[4*q] = v.x; ef[4*q+1] = v.y; ef[4*q+2] = v.z; ef[4*q+3] = v.w;
  }
  float best = 3.4e38f, second = 3.4e38f; int bi = 0;
  for (int q = 0; q < 4; ++q) {
    __syncthreads();
    for (int i = tid; i < 8192; i += 128) se[i] = emb[q * 8192 + i];
    __syncthreads();
    for (int k = 0; k < 128; ++k) {
      const float* cp = &se[k << 6];
      float p0 = 0.f, p1 = 0.f, p2 = 0.f, p3 = 0.f;
#pragma unroll
      for (int d = 0; d < 64; d += 4) {
        p0 = fmaf(ef[d],     cp[d],     p0);
        p1 = fmaf(ef[d + 1], cp[d + 1], p1);
        p2 = fmaf(ef[d + 2], cp[d + 2], p2);
        p3 = fmaf(ef[d + 3], cp[d + 3], p3);
      }
      float dot = (p0 + p1) + (p2 + p3);
      float d2 = (float)norms[q * 128 + k] - 2.f * dot;
      if (d2 < best) { second = best; best = d2; bi = q * 128 + k; }
      else if (d2 < second) { second = d2; }
    }
  }
  if (second - best < 5e-4f) {
    // exact f64 rescan (same 4-way-split summation order as the verified f64 kernel)
    double efd[64];
#pragma unroll
    for (int d = 0; d < 64; ++d) efd[d] = (double)ef[d];
    double bestd = 1e300; int bd = 0;
    for (int k = 0; k < 512; ++k) {
      const float* cp = &emb[(size_t)k << 6];
      double p0 = 0.0, p1 = 0.0, p2 = 0.0, p3 = 0.0;
#pragma unroll
      for (int d = 0; d < 64; d += 4) {
        p0 = fma(efd[d],     (double)cp[d],     p0);
        p1 = fma(efd[d + 1], (double)cp[d + 1], p1);
        p2 = fma(efd[d + 2], (double)cp[d + 2], p2);
        p3 = fma(efd[d + 3], (double)cp[d + 3], p3);
      }
      double dot = (p0 + p1) + (p2 + p3);
      double d2 = norms[k] - 2.0 * dot;
      if (d2 < bestd) { bestd = d2; bd = k; }
    }
    bi = bd;
  }
  cidx[r] = bi;
  closest_out[r] = (float)bi;
}

__global__ __launch_bounds__(256) void vq_gather(const float* __restrict__ enc, const float* __restrict__ emb,
                                                 const int* __restrict__ cidx, __hip_bfloat16* __restrict__ qot,
                                                 float* __restrict__ part) {
  int tid = threadIdx.x;
  int i = blockIdx.x * 256 + tid;
  int r = i >> 6, d = i & 63;
  int k = cidx[r];
  float q = emb[(k << 6) + d];
  float e = enc[i];
  int b = r >> 10;
  int f = ((r & 1023) << 6) + d;
  int d_orig = f >> 10, p = f & 1023;
  qot[(((size_t)(b << 10)) + p) * 64 + d_orig] = __float2bfloat16(q);
  float df = q - e;
  __shared__ float red[256];
  red[tid] = df * df;
  __syncthreads();
  for (int st = 128; st > 0; st >>= 1) {
    if (tid < st) red[tid] += red[tid + st];
    __syncthreads();
  }
  if (tid == 0) part[blockIdx.x] = red[0];
}

__global__ __launch_bounds__(256) void qloss_final(const float* __restrict__ part, float* __restrict__ out) {
  int tid = threadIdx.x;
  double s = 0.0;
  for (int i = tid; i < 8192; i += 256) s += part[i];
  __shared__ double red[256];
  red[tid] = s;
  __syncthreads();
  for (int st = 128; st > 0; st >>= 1) {
    if (tid < st) red[tid] += red[tid + st];
    __syncthreads();
  }
  if (tid == 0) {
    double mean = red[0] / 2097152.0;
    out[0] = (float)(1.25 * mean);
  }
}

// ---------------- host ----------------
extern "C" void kernel_launch(void* const* d_in, const int* in_sizes, int n_in,
                              void* d_out, int out_size, void* d_ws, size_t ws_size,
                              hipStream_t stream) {
  const float* x     = (const float*)d_in[0];
  const float* emb   = (const float*)d_in[1];
  const float* e_w1  = (const float*)d_in[2];
  const float* e_b1  = (const float*)d_in[3];
  const float* e_g1  = (const float*)d_in[4];
  const float* e_be1 = (const float*)d_in[5];
  const float* e_w2  = (const float*)d_in[6];
  const float* e_b2  = (const float*)d_in[7];
  const float* e_g2  = (const float*)d_in[8];
  const float* e_be2 = (const float*)d_in[9];
  const float* e_rw1 = (const float*)d_in[10];
  const float* e_rb1 = (const float*)d_in[11];
  const float* e_rg1 = (const float*)d_in[12];
  const float* e_rbe1= (const float*)d_in[13];
  const float* e_rw2 = (const float*)d_in[14];
  const float* e_rb2 = (const float*)d_in[15];
  const float* e_rg2 = (const float*)d_in[16];
  const float* e_rbe2= (const float*)d_in[17];
  const float* e_pw  = (const float*)d_in[18];
  const float* e_pb  = (const float*)d_in[19];
  const float* d_pw  = (const float*)d_in[20];
  const float* d_pb  = (const float*)d_in[21];
  const float* d_rw1 = (const float*)d_in[22];
  const float* d_rb1 = (const float*)d_in[23];
  const float* d_rg1 = (const float*)d_in[24];
  const float* d_rbe1= (const float*)d_in[25];
  const float* d_rw2 = (const float*)d_in[26];
  const float* d_rb2 = (const float*)d_in[27];
  const float* d_rg2 = (const float*)d_in[28];
  const float* d_rbe2= (const float*)d_in[29];
  const float* d_tw1 = (const float*)d_in[30];
  const float* d_tb1 = (const float*)d_in[31];
  const float* d_tg1 = (const float*)d_in[32];
  const float* d_tbe1= (const float*)d_in[33];
  const float* d_tw2 = (const float*)d_in[34];
  const float* d_tb2 = (const float*)d_in[35];

  float* ws   = (float*)d_ws;
  float* BIG  = ws + OFF_BIG;
  float* BP   = ws + OFF_BP;
  float* ENC  = ws + OFF_ENC;
  float* S    = ws + OFF_S;
  float* W2T  = ws + OFF_W2T;
  float* RW1T = ws + OFF_RW1T;
  float* RW2T = ws + OFF_RW2T;
  float* PWT  = ws + OFF_PWT;
  float* STATS= ws + OFF_STATS;
  double* NORM= (double*)(ws + OFF_NORM);
  int*   CIDX = (int*)(ws + OFF_CIDX);
  float* PART = ws + OFF_PART;
  float* STAT2= ws + OFF_STAT2;
  double* PARTD = (double*)(ws + OFF_STAT2);
  __hip_bfloat16* HT1  = (__hip_bfloat16*)(ws + OFF_HT1);
  __hip_bfloat16* HT2  = (__hip_bfloat16*)(ws + OFF_HT2);
  __hip_bfloat16* HT3  = (__hip_bfloat16*)(ws + OFF_HT3);
  __hip_bfloat16* QOT  = (__hip_bfloat16*)(ws + OFF_QOT);
  __hip_bfloat16* T9BT = (__hip_bfloat16*)(ws + OFF_BIG);
  __hip_bfloat16* DPWB = (__hip_bfloat16*)(ws + OFF_DPWB);
  __hip_bfloat16* DRW1B= (__hip_bfloat16*)(ws + OFF_DRW1B);
  __hip_bfloat16* DRW2B= (__hip_bfloat16*)(ws + OFF_DRW2B);
  __hip_bfloat16* TW1B = (__hip_bfloat16*)(ws + OFF_TW1B);
  __hip_bfloat16* WB   = (__hip_bfloat16*)(ws + OFF_WB);
  float* outp = (float*)d_out;

  dim3 blk(256);
  dim3 bn_grid(256, 8);

  prep_all<<<15746, blk, 0, stream>>>(e_w2, W2T, e_rw1, RW1T, e_rw2, RW2T, e_pw, PWT,
                                      d_tw2, WB, d_pw, DPWB, d_rw1, DRW1B, d_rw2, DRW2B,
                                      d_tw1, TW1B, emb, NORM);

  // ---- encoder (fp32) ----
  conv1_w<<<dim3(16, 32, 2), blk, 0, stream>>>(x, e_w1, e_b1, BIG);
  bn_stats_p<<<bn_grid, blk, 0, stream>>>(BIG, PARTD, 12, 32);
  bn_stats_f<<<1, blk, 0, stream>>>(PARTD, STATS, 131072);
  bn_apply<<<32768, blk, 0, stream>>>((float4*)BIG, nullptr, (float4*)BIG, STATS, e_g1, e_be1, 12, 8388608);
  conv_b64<2, 4><<<dim3(16, 2, 32), blk, 0, stream>>>(BIG, W2T, e_b2, S, 256, 256, 64, 64, 1);
  bn_stats_p<<<bn_grid, blk, 0, stream>>>(S, PARTD, 10, 32);
  bn_stats_f<<<1, blk, 0, stream>>>(PARTD, STATS, 32768);
  bn_apply<<<8192, blk, 0, stream>>>((float4*)S, nullptr, (float4*)S, STATS, e_g2, e_be2, 10, 2097152);
  conv_b64<1, 3><<<dim3(16, 2, 32), blk, 0, stream>>>(S, RW1T, e_rb1, BP, 256, 256, 32, 32, 1);
  bn_stats_p<<<bn_grid, blk, 0, stream>>>(BP, PARTD, 10, 32);
  bn_stats_f<<<1, blk, 0, stream>>>(PARTD, STATS, 32768);
  bn_apply<<<8192, blk, 0, stream>>>((float4*)BP, (float4*)S, (float4*)BP, STATS, e_rg1, e_rbe1, 10, 2097152);
  conv_b64<1, 1><<<dim3(16, 2, 32), blk, 0, stream>>>(BP, RW2T, e_rb2, S, 256, 256, 32, 32, 0);
  bn_stats_p<<<bn_grid, blk, 0, stream>>>(S, PARTD, 10, 32);
  bn_stats_f<<<1, blk, 0, stream>>>(PARTD, STATS, 32768);
  bn_apply<<<8192, blk, 0, stream>>>((float4*)S, (float4*)BP, (float4*)S, STATS, e_rg2, e_rbe2, 10, 2097152);
  conv_tiled<<<dim3(16, 1, 32), blk, 0, stream>>>(S, PWT, e_pb, ENC, 256, 64, 32, 32, 32, 32, 1, 1, 1, 0);

  // ---- VQ ----
  vq_argmin<<<256, dim3(128), 0, stream>>>(ENC, emb, NORM, CIDX, outp + OUT_CLOSEST);
  vq_gather<<<8192, blk, 0, stream>>>(ENC, emb, CIDX, QOT, PART);
  qloss_final<<<1, blk, 0, stream>>>(PART, outp + OUT_QLOSS);

  // ---- decoder (bf16 MFMA) ----
  mconv<64, 1, 1, 0><<<dim3(16, 4, 32), blk, 0, stream>>>(QOT, DPWB, d_pb, S, 256);
  fp32_to_bt<<<4096, blk, 0, stream>>>(S, HT1);
  mconv_s<<<dim3(16, 4, 32), blk, 0, stream>>>(HT1, DRW1B, d_rb1, BP);
  bn_stats_p<<<bn_grid, blk, 0, stream>>>(BP, PARTD, 10, 32);
  bn_stats_f<<<1, blk, 0, stream>>>(PARTD, STATS, 32768);
  bn_apply_td<<<4096, blk, 0, stream>>>(BP, S, S, HT2, STATS, d_rg1, d_rbe1);
  mconv_s<<<dim3(16, 4, 32), blk, 0, stream>>>(HT2, DRW2B, d_rb2, BP);
  bn_stats_p<<<bn_grid, blk, 0, stream>>>(BP, PARTD, 10, 32);
  bn_stats_f<<<1, blk, 0, stream>>>(PARTD, STATS, 32768);
  bn_apply_td<<<4096, blk, 0, stream>>>(BP, S, nullptr, HT3, STATS, d_rg2, d_rbe2);
  mdeconv_s<<<dim3(16, 4, 32), blk, 0, stream>>>(HT3, TW1B, d_tb1, T9BT);
  bnbt_stage1<<<64, blk, 0, stream>>>(T9BT, STAT2);
  bnbt_stage2<<<1, blk, 0, stream>>>(STAT2, STATS);
  bn_apply_bt<<<16384, blk, 0, stream>>>(T9BT, STATS, d_tg1, d_tbe1);
  deconv_mfma<<<2048, blk, 0, stream>>>(T9BT, WB, d_tb2, outp);
}

// Round 17
// 2757.451 us; speedup vs baseline: 1.0954x; 1.0954x over previous
//
#include <hip/hip_runtime.h>
#include <hip/hip_bf16.h>
#include <math.h>

// B=32, HID=256, D=64, K=512
// Encoder fp32 (argmin exactness); decoder bf16 MFMA (post-VQ, lenient threshold).

#define OUT_CLOSEST 1572864
#define OUT_QLOSS   1605632

// ---- ws offsets (in floats) ----
#define OFF_BIG   0u
#define OFF_BP    0u
#define OFF_ENC   8388608u
#define OFF_HT1   8388608u
#define OFF_HT2   12582912u
#define OFF_HT3   16777216u
#define OFF_QOT   20971520u
#define OFF_S     33554432u
#define OFF_W2T   41943040u
#define OFF_RW1T  42991616u
#define OFF_RW2T  43581440u
#define OFF_PWT   43646976u
#define OFF_DPWB  43675648u
#define OFF_DRW1B 43683840u
#define OFF_DRW2B 43978752u
#define OFF_TW1B  44273664u
#define OFF_STATS 44797952u
#define OFF_NORM  44798464u
#define OFF_CIDX  44799488u
#define OFF_PART  44832256u
#define OFF_STAT2 44840448u   // also double[4096] for bn partials (time-disjoint)
#define OFF_WB    44873216u   // bf16 65536 (32768 fl): padded L10 weights

typedef __bf16 bf16x8 __attribute__((ext_vector_type(8)));
typedef float f32x4 __attribute__((ext_vector_type(4)));

__device__ __forceinline__ unsigned short f2bf(float f) {
  __hip_bfloat16 h = __float2bfloat16(f);
  return *reinterpret_cast<unsigned short*>(&h);
}
__device__ __forceinline__ float bf2f(unsigned short u) {
  return __uint_as_float((unsigned)u << 16);
}

// ---------------- one-shot prep: all weight permutes + codebook norms ----------------
__global__ __launch_bounds__(256) void prep_all(
    const float* __restrict__ e_w2, float* __restrict__ W2T,
    const float* __restrict__ e_rw1, float* __restrict__ RW1T,
    const float* __restrict__ e_rw2, float* __restrict__ RW2T,
    const float* __restrict__ e_pw, float* __restrict__ PWT,
    const float* __restrict__ d_tw2, __hip_bfloat16* __restrict__ WB,
    const float* __restrict__ d_pw, __hip_bfloat16* __restrict__ DPWB,
    const float* __restrict__ d_rw1, __hip_bfloat16* __restrict__ DRW1B,
    const float* __restrict__ d_rw2, __hip_bfloat16* __restrict__ DRW2B,
    const float* __restrict__ d_tw1, __hip_bfloat16* __restrict__ TW1B,
    const float* __restrict__ emb, double* __restrict__ NORM) {
  const int bid = blockIdx.x, tid = threadIdx.x;
  if (bid < 4096) {
    int i = bid * 256 + tid;
    int co = i & 255; int r = i >> 8; int ci = r & 255; int t = r >> 8;
    W2T[i] = e_w2[((size_t)co * 256 + ci) * 16 + t];
  } else if (bid < 6400) {
    int i = (bid - 4096) * 256 + tid;
    if (i < 589824) {
      int co = i % 256; int r = i / 256; int ci = r % 256; int t = r / 256;
      RW1T[i] = e_rw1[((size_t)co * 256 + ci) * 9 + t];
    }
  } else if (bid < 6656) {
    int i = (bid - 6400) * 256 + tid;
    int co = i & 255; int ci = i >> 8;
    RW2T[i] = e_rw2[(size_t)co * 256 + ci];
  } else if (bid < 6720) {
    int i = (bid - 6656) * 256 + tid;
    int co = i & 63; int ci = i >> 6;
    PWT[i] = e_pw[(size_t)co * 256 + ci];
  } else if (bid < 6976) {
    int i = (bid - 6720) * 256 + tid;
    int e = i & 7; int ln = (i >> 3) & 15; int ciq = (i >> 7) & 31; int t = i >> 12;
    int ci = ciq * 8 + e;
    float v = (ln < 3) ? d_tw2[((size_t)ci * 3 + ln) * 16 + t] : 0.f;
    WB[i] = __float2bfloat16(v);
  } else if (bid < 7040) {
    int i = (bid - 6976) * 256 + tid;
    int ci = i & 63; int co = i >> 6;
    DPWB[i] = __float2bfloat16(d_pw[(size_t)co * 64 + ci]);
  } else if (bid < 9344) {
    int i = (bid - 7040) * 256 + tid;
    if (i < 589824) {
      int ci = i % 256; int r = i / 256; int co = r % 256; int t = r / 256;
      DRW1B[i] = __float2bfloat16(d_rw1[((size_t)co * 256 + ci) * 9 + t]);
    }
  } else if (bid < 11648) {
    int i = (bid - 9344) * 256 + tid;
    if (i < 589824) {
      int ci = i % 256; int r = i / 256; int co = r % 256; int t = r / 256;
      DRW2B[i] = __float2bfloat16(d_rw2[((size_t)co * 256 + ci) * 9 + t]);
    }
  } else if (bid < 15744) {
    int i = (bid - 11648) * 256 + tid;
    int ci = i & 255; int r = i >> 8; int co = r & 255; int t = r >> 8;
    TW1B[i] = __float2bfloat16(d_tw1[((size_t)ci * 256 + co) * 16 + t]);
  } else {
    int k = (bid - 15744) * 256 + tid;
    if (k < 512) {
      double s = 0.0;
      for (int d = 0; d < 64; ++d) { double e = emb[(k << 6) + d]; s += e * e; }
      NORM[k] = s;
    }
  }
}

// ---------------- L1 conv: strip-tiled, co-split (4 blocks/CU) ----------------
__global__ __launch_bounds__(256) void conv1_w(const float* __restrict__ x, const float* __restrict__ w,
                                               const float* __restrict__ bias, float* __restrict__ out) {
  __shared__ float ws[6144];
  __shared__ float xs[3][10][132];
  const int tid = threadIdx.x;
  const int s = blockIdx.x, b = blockIdx.y, ch = blockIdx.z;
  for (int i = tid; i < 1536; i += 256)
    *(float4*)&ws[i * 4] = *(const float4*)&w[ch * 6144 + i * 4];
  for (int i = tid; i < 3 * 10 * 130; i += 256) {
    int col = i % 130; int r2 = i / 130; int lr = r2 % 10; int ci = r2 / 10;
    int ih = 8 * s - 1 + lr; int iw = col - 1;
    float v = 0.f;
    if ((unsigned)ih < 128u && (unsigned)iw < 128u)
      v = x[((size_t)(b * 3 + ci) << 14) + (ih << 7) + iw];
    xs[ci][lr][col] = v;
  }
  __syncthreads();
  const int ohl = tid >> 6, ow = tid & 63;
  const int oh = (s << 2) + ohl;
  float xr[48];
#pragma unroll
  for (int ci = 0; ci < 3; ++ci)
#pragma unroll
    for (int kh = 0; kh < 4; ++kh)
#pragma unroll
      for (int kw = 0; kw < 4; ++kw)
        xr[(ci * 4 + kh) * 4 + kw] = xs[ci][2 * ohl + kh][2 * ow + kw];
  float* op = out + (((size_t)b * 256) << 12) + (oh << 6) + ow;
  for (int co = 0; co < 128; ++co) {
    float acc = bias[ch * 128 + co];
    const float* wp = &ws[co * 48];
#pragma unroll
    for (int k = 0; k < 48; k += 4) {
      float4 wv = *(const float4*)&wp[k];
      acc = fmaf(xr[k], wv.x, acc);
      acc = fmaf(xr[k + 1], wv.y, acc);
      acc = fmaf(xr[k + 2], wv.z, acc);
      acc = fmaf(xr[k + 3], wv.w, acc);
    }
    op[(size_t)(ch * 128 + co) << 12] = acc;
  }
}

// ---------------- BN stats: two-stage, deterministic ----------------
__global__ __launch_bounds__(256) void bn_stats_p(const float* __restrict__ in, double* __restrict__ part,
                                                  int log2HW, int Bn) {
  int c = blockIdx.x, g = blockIdx.y;
  int tid = threadIdx.x;
  int HW = 1 << log2HW;
  int cnt = Bn << log2HW;
  int seg = cnt >> 3;
  double s = 0.0, s2 = 0.0;
  for (int i = g * seg + tid; i < (g + 1) * seg; i += 256) {
    int b = i >> log2HW, p = i & (HW - 1);
    float v = in[((size_t)(b * 256 + c) << log2HW) + p];
    s += v; s2 += (double)v * v;
  }
  __shared__ double r1[256], r2[256];
  r1[tid] = s; r2[tid] = s2;
  __syncthreads();
  for (int st = 128; st > 0; st >>= 1) {
    if (tid < st) { r1[tid] += r1[tid + st]; r2[tid] += r2[tid + st]; }
    __syncthreads();
  }
  if (tid == 0) {
    part[(c << 3) + g] = r1[0];
    part[2048 + (c << 3) + g] = r2[0];
  }
}
__global__ __launch_bounds__(256) void bn_stats_f(const double* __restrict__ part, float* __restrict__ stats,
                                                  int cnt) {
  int c = threadIdx.x;
  double s = 0.0, s2 = 0.0;
  for (int g = 0; g < 8; ++g) { s += part[(c << 3) + g]; s2 += part[2048 + (c << 3) + g]; }
  double m = s / cnt;
  double var = s2 / cnt - m * m;
  stats[c] = (float)m;
  stats[256 + c] = (float)(1.0 / sqrt(var + 1e-5));
}

__global__ __launch_bounds__(256) void bn_apply(const float4* __restrict__ in, const float4* __restrict__ res,
                                                float4* __restrict__ out, const float* __restrict__ stats,
                                                const float* __restrict__ g, const float* __restrict__ be,
                                                int log2HW, int n4) {
  int i = blockIdx.x * 256 + threadIdx.x;
  if (i >= n4) return;
  int c = (i >> (log2HW - 2)) & 255;
  float sc = stats[256 + c] * g[c];
  float sh = be[c] - stats[c] * sc;
  float4 v = in[i];
  float4 o;
  o.x = fmaxf(fmaf(v.x, sc, sh), 0.f);
  o.y = fmaxf(fmaf(v.y, sc, sh), 0.f);
  o.z = fmaxf(fmaf(v.z, sc, sh), 0.f);
  o.w = fmaxf(fmaf(v.w, sc, sh), 0.f);
  if (res) { float4 r = res[i]; o.x += r.x; o.y += r.y; o.z += r.z; o.w += r.w; }
  out[i] = o;
}

// BN+ReLU+res for decoder 32x32 layers
__global__ __launch_bounds__(256) void bn_apply_td(const float* __restrict__ in, const float* __restrict__ res,
                                                   float* __restrict__ out_f, __hip_bfloat16* __restrict__ out_bt,
                                                   const float* __restrict__ stats, const float* __restrict__ g,
                                                   const float* __restrict__ be) {
  int j = blockIdx.x * 256 + threadIdx.x;
  int sp = j & 1023, cg = (j >> 10) & 31, b = j >> 15;
  unsigned short us[8];
#pragma unroll
  for (int q = 0; q < 8; ++q) {
    int c = cg * 8 + q;
    float sc = stats[256 + c] * g[c];
    float sh = be[c] - stats[c] * sc;
    size_t idx = ((size_t)(b * 256 + c) << 10) + sp;
    float y = fmaxf(fmaf(in[idx], sc, sh), 0.f) + res[idx];
    if (out_f) out_f[idx] = y;
    us[q] = f2bf(y);
  }
  ushort4* op = (ushort4*)(out_bt + (((size_t)(b << 10) + sp) << 8) + cg * 8);
  op[0] = make_ushort4(us[0], us[1], us[2], us[3]);
  op[1] = make_ushort4(us[4], us[5], us[6], us[7]);
}

// fp32 NCHW (32,256,1024) -> bf16 (b, sp, c)
__global__ __launch_bounds__(256) void fp32_to_bt(const float* __restrict__ in, __hip_bfloat16* __restrict__ out) {
  int j = blockIdx.x * 256 + threadIdx.x;
  int sp = j & 1023, cg = (j >> 10) & 31, b = j >> 15;
  unsigned short us[8];
#pragma unroll
  for (int q = 0; q < 8; ++q) {
    int c = cg * 8 + q;
    us[q] = f2bf(in[((size_t)(b * 256 + c) << 10) + sp]);
  }
  ushort4* op = (ushort4*)(out + (((size_t)(b << 10) + sp) << 8) + cg * 8);
  op[0] = make_ushort4(us[0], us[1], us[2], us[3]);
  op[1] = make_ushort4(us[4], us[5], us[6], us[7]);
}

// ---------------- MFMA conv (decoder 1x1, CI=64) ----------------
template<int CI, int KH, int KW, int PAD>
__global__ __launch_bounds__(256) void mconv(const __hip_bfloat16* __restrict__ act,
                                             const __hip_bfloat16* __restrict__ wt,
                                             const float* __restrict__ bias,
                                             float* __restrict__ out, int CO) {
  const int tid = threadIdx.x;
  const int lane = tid & 63, wv = tid >> 6;
  const int ln = lane & 15, kg = lane >> 4;
  const int b = blockIdx.z;
  const int co_base = blockIdx.y << 6;
  const int sp_base = blockIdx.x << 6;
  const int co_n = co_base + wv * 16 + ln;
  int oh[4], ow[4];
#pragma unroll
  for (int mf = 0; mf < 4; ++mf) {
    int s = sp_base + mf * 16 + ln;
    oh[mf] = s >> 5; ow[mf] = s & 31;
  }
  f32x4 acc[4] = {{0,0,0,0},{0,0,0,0},{0,0,0,0},{0,0,0,0}};
  const size_t actb = (size_t)b * 1024 * CI;
  const int kg8 = kg * 8;
  for (int kh = 0; kh < KH; ++kh)
    for (int kw = 0; kw < KW; ++kw) {
      const int t = kh * KW + kw;
      const __hip_bfloat16* bp = wt + ((size_t)t * CO + co_n) * CI + kg8;
      const __hip_bfloat16* ap[4]; bool val[4];
#pragma unroll
      for (int mf = 0; mf < 4; ++mf) {
        int ih = oh[mf] + kh - PAD, iw = ow[mf] + kw - PAD;
        val[mf] = ((unsigned)ih < 32u) && ((unsigned)iw < 32u);
        ap[mf] = val[mf] ? (act + actb + (size_t)((ih << 5) + iw) * CI + kg8) : (act + actb + kg8);
      }
#pragma unroll
      for (int ci0 = 0; ci0 < CI; ci0 += 32) {
        bf16x8 bf = *(const bf16x8*)(bp + ci0);
        bf16x8 af[4];
#pragma unroll
        for (int mf = 0; mf < 4; ++mf) {
          bf16x8 z = {};
          bf16x8 tv = *(const bf16x8*)(ap[mf] + ci0);
          af[mf] = val[mf] ? tv : z;
        }
#pragma unroll
        for (int mf = 0; mf < 4; ++mf)
          acc[mf] = __builtin_amdgcn_mfma_f32_16x16x32_bf16(af[mf], bf, acc[mf], 0, 0, 0);
      }
    }
  float bv = bias[co_n];
#pragma unroll
  for (int mf = 0; mf < 4; ++mf) {
    int sp_r = sp_base + mf * 16 + kg * 4;
    float4 r = make_float4(acc[mf][0] + bv, acc[mf][1] + bv, acc[mf][2] + bv, acc[mf][3] + bv);
    *(float4*)&out[((size_t)(b * CO + co_n) << 10) + sp_r] = r;
  }
}

// ---------------- MFMA 3x3 conv with LDS-staged act (CI=256, CO=256, pad 1) ----------------
__global__ __launch_bounds__(256, 4) void mconv_s(const __hip_bfloat16* __restrict__ act,
                                                  const __hip_bfloat16* __restrict__ wt,
                                                  const float* __restrict__ bias,
                                                  float* __restrict__ out) {
  __shared__ __hip_bfloat16 As[4 * 34 * 136];   // 36 KB
  const int tid = threadIdx.x;
  const int lane = tid & 63, wv = tid >> 6;
  const int ln = lane & 15, kg = lane >> 4;
  const int b = blockIdx.z;
  const int co_base = blockIdx.y << 6;
  const int sp_base = blockIdx.x << 6;
  const int co_n = co_base + wv * 16 + ln;
  const int r_first = (sp_base >> 5) - 1;
  const size_t actb = (size_t)b << 18;
  const int kg8 = kg * 8;

  f32x4 acc[4] = {{0,0,0,0},{0,0,0,0},{0,0,0,0},{0,0,0,0}};

  int lr0[4], lc0[4];
#pragma unroll
  for (int mf = 0; mf < 4; ++mf) {
    int s = mf * 16 + ln;
    lr0[mf] = s >> 5;
    lc0[mf] = s & 31;
  }

  for (int cih = 0; cih < 2; ++cih) {
    __syncthreads();
    for (int sIdx = tid; sIdx < 2176; sIdx += 256) {
      int v8 = sIdx & 15;
      int rc = sIdx >> 4;
      int col = rc % 34;
      int row = rc / 34;
      int ih = r_first + row;
      int iw = col - 1;
      uint4 val = make_uint4(0, 0, 0, 0);
      if ((unsigned)ih < 32u && (unsigned)iw < 32u)
        val = *(const uint4*)(act + actb + ((size_t)((ih << 5) + iw) << 8) + cih * 128 + v8 * 8);
      *(uint4*)(&As[rc * 136 + v8 * 8]) = val;
    }
    __syncthreads();
#pragma unroll
    for (int kh = 0; kh < 3; ++kh)
#pragma unroll
      for (int kw = 0; kw < 3; ++kw) {
        const int t = kh * 3 + kw;
        const __hip_bfloat16* bp = wt + ((size_t)t * 256 + co_n) * 256 + cih * 128 + kg8;
#pragma unroll
        for (int c32 = 0; c32 < 4; ++c32) {
          bf16x8 bf = *(const bf16x8*)(bp + (c32 << 5));
#pragma unroll
          for (int mf = 0; mf < 4; ++mf) {
            int lrow = lr0[mf] + kh;
            int lcol = lc0[mf] + kw;
            bf16x8 af = *(const bf16x8*)(&As[(lrow * 34 + lcol) * 136 + (c32 << 5) + kg8]);
            acc[mf] = __builtin_amdgcn_mfma_f32_16x16x32_bf16(af, bf, acc[mf], 0, 0, 0);
          }
        }
      }
  }
  float bv = bias[co_n];
#pragma unroll
  for (int mf = 0; mf < 4; ++mf) {
    int sp_r = sp_base + mf * 16 + kg * 4;
    float4 r = make_float4(acc[mf][0] + bv, acc[mf][1] + bv, acc[mf][2] + bv, acc[mf][3] + bv);
    *(float4*)&out[((size_t)(b * 256 + co_n) << 10) + sp_r] = r;
  }
}

// ---------------- MFMA deconv L9, PHASE-FUSED + LDS-staged act ----------------
__global__ __launch_bounds__(256) void mdeconv_s(const __hip_bfloat16* __restrict__ act,
                                                 const __hip_bfloat16* __restrict__ wt,
                                                 const float* __restrict__ bias,
                                                 __hip_bfloat16* __restrict__ out) {
  __shared__ __hip_bfloat16 As[4 * 34 * 136];   // 36 KB
  const int tid = threadIdx.x;
  const int lane = tid & 63, wv = tid >> 6;
  const int ln = lane & 15, kg = lane >> 4;
  const int b = blockIdx.z;
  const int co_base = blockIdx.y << 6;
  const int sp_base = blockIdx.x << 6;
  const int co_a = co_base + wv * 16 + ln;
  const int r_first = (sp_base >> 5) - 1;
  const size_t actb = (size_t)b << 18;
  const int kg8 = kg * 8;

  int lr0[4], lc0[4];
#pragma unroll
  for (int mf = 0; mf < 4; ++mf) {
    int s = mf * 16 + ln;
    lr0[mf] = s >> 5;
    lc0[mf] = s & 31;
  }

  f32x4 acc[16];
#pragma unroll
  for (int q = 0; q < 16; ++q) acc[q] = (f32x4){0, 0, 0, 0};

  const int nmem[3]     = {1, 2, 1};
  const int khm[3][2]   = {{3, 0}, {1, 2}, {0, 0}};
  const int phm[3][2]   = {{0, 0}, {0, 1}, {1, 0}};

  for (int cih = 0; cih < 2; ++cih) {
    __syncthreads();
    for (int sIdx = tid; sIdx < 2176; sIdx += 256) {
      int v8 = sIdx & 15;
      int rc = sIdx >> 4;
      int col = rc % 34;
      int row = rc / 34;
      int ih = r_first + row;
      int iw = col - 1;
      uint4 val = make_uint4(0, 0, 0, 0);
      if ((unsigned)ih < 32u && (unsigned)iw < 32u)
        val = *(const uint4*)(act + actb + ((size_t)((ih << 5) + iw) << 8) + cih * 128 + v8 * 8);
      *(uint4*)(&As[rc * 136 + v8 * 8]) = val;
    }
    __syncthreads();
#pragma unroll
    for (int di = 0; di < 3; ++di) {
#pragma unroll
      for (int dj = 0; dj < 3; ++dj) {
#pragma unroll
        for (int u = 0; u < 2; ++u) {
          if (u < nmem[di]) {
#pragma unroll
            for (int v = 0; v < 2; ++v) {
              if (v < nmem[dj]) {
                const int t = khm[di][u] * 4 + khm[dj][v];
                const int pidx = (phm[di][u] * 2 + phm[dj][v]) << 2;
                const __hip_bfloat16* bp = wt + ((size_t)t * 256 + co_a) * 256 + cih * 128 + kg8;
#pragma unroll
                for (int c32 = 0; c32 < 4; ++c32) {
                  bf16x8 af = *(const bf16x8*)(bp + (c32 << 5));
#pragma unroll
                  for (int mf = 0; mf < 4; ++mf) {
                    int lrow = lr0[mf] + di;
                    int lcol = lc0[mf] + dj;
                    bf16x8 bfr = *(const bf16x8*)(&As[(lrow * 34 + lcol) * 136 + (c32 << 5) + kg8]);
                    acc[pidx + mf] = __builtin_amdgcn_mfma_f32_16x16x32_bf16(af, bfr, acc[pidx + mf], 0, 0, 0);
                  }
                }
              }
            }
          }
        }
      }
    }
  }
  const int co_r = co_base + wv * 16 + kg * 4;
  float b0 = bias[co_r], b1 = bias[co_r + 1], b2 = bias[co_r + 2], b3 = bias[co_r + 3];
#pragma unroll
  for (int ph = 0; ph < 2; ++ph)
#pragma unroll
    for (int pw = 0; pw < 2; ++pw) {
      const int pidx = (ph * 2 + pw) << 2;
#pragma unroll
      for (int mf = 0; mf < 4; ++mf) {
        int s = sp_base + mf * 16 + ln;
        int a = s >> 5, c = s & 31;
        size_t obase = (((size_t)(b << 12)) + (((a << 1) + ph) << 6) + (c << 1) + pw) << 8;
        f32x4 av = acc[pidx + mf];
        ushort4 u = make_ushort4(f2bf(av[0] + b0), f2bf(av[1] + b1),
                                 f2bf(av[2] + b2), f2bf(av[3] + b3));
        *(ushort4*)(out + obase + co_r) = u;
      }
    }
}

// ---------------- BN stats over bf16 transposed (b, 4096, 256) ----------------
__global__ __launch_bounds__(256) void bnbt_stage1(const __hip_bfloat16* __restrict__ in, float* __restrict__ part) {
  int t = threadIdx.x, blk = blockIdx.x;
  float s[8] = {0,0,0,0,0,0,0,0}, s2[8] = {0,0,0,0,0,0,0,0};
  size_t base = ((size_t)blk * 256 + t) * 8;
  const size_t stride = 64 * 256 * 8;
  for (int it = 0; it < 256; ++it) {
    ushort4 u0 = *(const ushort4*)(in + base);
    ushort4 u1 = *(const ushort4*)(in + base + 4);
    float v[8] = {bf2f(u0.x), bf2f(u0.y), bf2f(u0.z), bf2f(u0.w),
                  bf2f(u1.x), bf2f(u1.y), bf2f(u1.z), bf2f(u1.w)};
#pragma unroll
    for (int q = 0; q < 8; ++q) { s[q] += v[q]; s2[q] += v[q] * v[q]; }
    base += stride;
  }
  __shared__ float ls[256][8], ls2[256][8];
#pragma unroll
  for (int q = 0; q < 8; ++q) { ls[t][q] = s[q]; ls2[t][q] = s2[q]; }
  __syncthreads();
  if (t < 32) {
#pragma unroll
    for (int q = 0; q < 8; ++q) {
      float a = 0.f, a2 = 0.f;
      for (int r = 0; r < 8; ++r) { a += ls[t + 32 * r][q]; a2 += ls2[t + 32 * r][q]; }
      part[blk * 256 + t * 8 + q] = a;
      part[16384 + blk * 256 + t * 8 + q] = a2;
    }
  }
}

__global__ __launch_bounds__(256) void bnbt_stage2(const float* __restrict__ part, float* __restrict__ stats) {
  int c = threadIdx.x;
  double s = 0.0, s2 = 0.0;
  for (int q = 0; q < 64; ++q) { s += part[q * 256 + c]; s2 += part[16384 + q * 256 + c]; }
  double m = s / 131072.0;
  double var = s2 / 131072.0 - m * m;
  stats[c] = (float)m;
  stats[256 + c] = (float)(1.0 / sqrt(var + 1e-5));
}

__global__ __launch_bounds__(256) void bn_apply_bt(__hip_bfloat16* __restrict__ io, const float* __restrict__ stats,
                                                   const float* __restrict__ g, const float* __restrict__ be) {
  int i = blockIdx.x * 256 + threadIdx.x;
  size_t off = (size_t)i * 8;
  int c0 = (i & 31) * 8;
  ushort4 u0 = *(const ushort4*)(io + off);
  ushort4 u1 = *(const ushort4*)(io + off + 4);
  float v[8] = {bf2f(u0.x), bf2f(u0.y), bf2f(u0.z), bf2f(u0.w),
                bf2f(u1.x), bf2f(u1.y), bf2f(u1.z), bf2f(u1.w)};
  unsigned short us[8];
#pragma unroll
  for (int q = 0; q < 8; ++q) {
    int c = c0 + q;
    float sc = stats[256 + c] * g[c];
    float sh = be[c] - stats[c] * sc;
    us[q] = f2bf(fmaxf(fmaf(v[q], sc, sh), 0.f));
  }
  *(ushort4*)(io + off) = make_ushort4(us[0], us[1], us[2], us[3]);
  *(ushort4*)(io + off + 4) = make_ushort4(us[4], us[5], us[6], us[7]);
}

// ---------------- encoder conv: 128co x 64sp tile, 8co x 4sp per thread ----------------
template<int STRIDE, int KK>
__global__ __launch_bounds__(256, 4) void conv_b64(
    const float* __restrict__ in, const float* __restrict__ wt,
    const float* __restrict__ bias, float* __restrict__ out,
    int CI, int CO, int Hin, int Win, int pad) {
  __shared__ float Xs[2][16][64];
  __shared__ float Ws[2][16][128];
  const int tid = threadIdx.x;
  const int cb = tid & 15, sb = tid >> 4;
  const int sx = tid >> 4;
  const int cx = (tid & 15) << 2;
  const int tw = tid >> 5;
  const int ww = (tid & 31) << 2;
  const int b = blockIdx.z;
  const int co0 = blockIdx.y << 7;
  const int sp0 = blockIdx.x << 6;
  const int HWin = Hin * Win;
  const int nst = KK * KK * 16;

  int oh_s[4], ow_s[4];
#pragma unroll
  for (int q = 0; q < 4; ++q) {
    int s = sp0 + cx + q;
    oh_s[q] = s >> 5; ow_s[q] = s & 31;
  }

  float acc[8][4];
#pragma unroll
  for (int i = 0; i < 8; ++i)
#pragma unroll
    for (int j = 0; j < 4; ++j) acc[i][j] = 0.f;

  float pv[4];
  float4 pw0, pw1;

  auto gather = [&](int st) {
    int t = st >> 4;
    int ci0 = (st & 15) << 4;
    int kh = t / KK, kw = t - kh * KK;
    const float* ib = in + (size_t)(b * CI + ci0 + sx) * HWin;
#pragma unroll
    for (int q = 0; q < 4; ++q) {
      int ih = oh_s[q] * STRIDE + kh - pad;
      int iw = ow_s[q] * STRIDE + kw - pad;
      bool ok = ((unsigned)ih < (unsigned)Hin) && ((unsigned)iw < (unsigned)Win);
      pv[q] = ok ? ib[ih * Win + iw] : 0.f;
    }
    const float* wb = wt + ((size_t)t * CI + ci0 + tw) * CO + co0 + ww;
    pw0 = *(const float4*)wb;
    pw1 = *(const float4*)(wb + (size_t)8 * CO);
  };

  gather(0);
  *(float4*)&Xs[0][sx][cx]     = make_float4(pv[0], pv[1], pv[2], pv[3]);
  *(float4*)&Ws[0][tw][ww]     = pw0;
  *(float4*)&Ws[0][tw + 8][ww] = pw1;
  __syncthreads();

  for (int st = 0; st < nst; ++st) {
    const int cur = st & 1;
    const bool more = (st + 1 < nst);
    if (more) gather(st + 1);
    const float (*Xc)[64]  = Xs[cur];
    const float (*Wc)[128] = Ws[cur];
#pragma unroll 4
    for (int ci = 0; ci < 16; ++ci) {
      float4 w0 = *(const float4*)&Wc[ci][cb << 2];
      float4 w1 = *(const float4*)&Wc[ci][64 + (cb << 2)];
      float4 xv = *(const float4*)&Xc[ci][sb << 2];
#define FMA_ROW(I, WC) \
      acc[I][0] = fmaf(WC, xv.x, acc[I][0]); \
      acc[I][1] = fmaf(WC, xv.y, acc[I][1]); \
      acc[I][2] = fmaf(WC, xv.z, acc[I][2]); \
      acc[I][3] = fmaf(WC, xv.w, acc[I][3]);
      FMA_ROW(0, w0.x) FMA_ROW(1, w0.y) FMA_ROW(2, w0.z) FMA_ROW(3, w0.w)
      FMA_ROW(4, w1.x) FMA_ROW(5, w1.y) FMA_ROW(6, w1.z) FMA_ROW(7, w1.w)
#undef FMA_ROW
    }
    if (more) {
      const int nxt = cur ^ 1;
      *(float4*)&Xs[nxt][sx][cx]     = make_float4(pv[0], pv[1], pv[2], pv[3]);
      *(float4*)&Ws[nxt][tw][ww]     = pw0;
      *(float4*)&Ws[nxt][tw + 8][ww] = pw1;
      __syncthreads();
    }
  }

#pragma unroll
  for (int i = 0; i < 8; ++i) {
    int co = co0 + ((i < 4) ? (cb << 2) + i : 64 + (cb << 2) + (i - 4));
    float bv = bias[co];
    *(float4*)&out[((size_t)(b * CO + co) << 10) + sp0 + (sb << 2)] =
        make_float4(acc[i][0] + bv, acc[i][1] + bv, acc[i][2] + bv, acc[i][3] + bv);
  }
}

// ---------------- encoder tiled conv (fp32, for L5 CO=64) ----------------
__device__ __forceinline__ void tile_fma(const float* Ws_, const float* Xs_, int co4, int sp4,
                                         float acc[4][4]) {
#pragma unroll
  for (int ci = 0; ci < 16; ++ci) {
    float4 wv = *(const float4*)(Ws_ + (ci << 6) + co4);
    float4 xv = *(const float4*)(Xs_ + (ci << 6) + sp4);
    acc[0][0] = fmaf(xv.x, wv.x, acc[0][0]);
    acc[0][1] = fmaf(xv.x, wv.y, acc[0][1]);
    acc[0][2] = fmaf(xv.x, wv.z, acc[0][2]);
    acc[0][3] = fmaf(xv.x, wv.w, acc[0][3]);
    acc[1][0] = fmaf(xv.y, wv.x, acc[1][0]);
    acc[1][1] = fmaf(xv.y, wv.y, acc[1][1]);
    acc[1][2] = fmaf(xv.y, wv.z, acc[1][2]);
    acc[1][3] = fmaf(xv.y, wv.w, acc[1][3]);
    acc[2][0] = fmaf(xv.z, wv.x, acc[2][0]);
    acc[2][1] = fmaf(xv.z, wv.y, acc[2][1]);
    acc[2][2] = fmaf(xv.z, wv.z, acc[2][2]);
    acc[2][3] = fmaf(xv.z, wv.w, acc[2][3]);
    acc[3][0] = fmaf(xv.w, wv.x, acc[3][0]);
    acc[3][1] = fmaf(xv.w, wv.y, acc[3][1]);
    acc[3][2] = fmaf(xv.w, wv.z, acc[3][2]);
    acc[3][3] = fmaf(xv.w, wv.w, acc[3][3]);
  }
}

__global__ __launch_bounds__(256) void conv_tiled(
    const float* __restrict__ in, const float* __restrict__ wt,
    const float* __restrict__ bias, float* __restrict__ out,
    int CI, int CO, int Hin, int Win, int Hout, int Wout,
    int KH, int KW, int stride, int pad) {
  __shared__ float Xs[16 * 64];
  __shared__ float Ws[16 * 64];
  const int tid = threadIdx.x;
  const int b = blockIdx.z;
  const int co_base = blockIdx.y << 6;
  const int sp_base = blockIdx.x << 6;
  const int lo = tid & 15, hi = tid >> 4;
  const int co4 = lo << 2, sp4 = hi << 2;
  const int HWin = Hin * Win, HWout = Hout * Wout;

  int oh0[4], ow0[4];
#pragma unroll
  for (int j = 0; j < 4; ++j) {
    int s = sp_base + (lo << 2) + j;
    oh0[j] = s / Wout; ow0[j] = s - oh0[j] * Wout;
  }
  float acc[4][4] = {{0.f,0.f,0.f,0.f},{0.f,0.f,0.f,0.f},{0.f,0.f,0.f,0.f},{0.f,0.f,0.f,0.f}};

  for (int kh = 0; kh < KH; ++kh)
    for (int kw = 0; kw < KW; ++kw) {
      const int t = kh * KW + kw;
      for (int ci0 = 0; ci0 < CI; ci0 += 16) {
        const float* ib = in + (size_t)(b * CI + ci0 + hi) * HWin;
        float v[4];
#pragma unroll
        for (int j = 0; j < 4; ++j) {
          int ih = oh0[j] * stride + kh - pad;
          int iw = ow0[j] * stride + kw - pad;
          v[j] = 0.f;
          if ((unsigned)ih < (unsigned)Hin && (unsigned)iw < (unsigned)Win)
            v[j] = ib[ih * Win + iw];
        }
        *(float4*)&Xs[(hi << 6) + (lo << 2)] = make_float4(v[0], v[1], v[2], v[3]);
        *(float4*)&Ws[(hi << 6) + (lo << 2)] =
            *(const float4*)&wt[((size_t)t * CI + ci0 + hi) * CO + co_base + (lo << 2)];
        __syncthreads();
        tile_fma(Ws, Xs, co4, sp4, acc);
        __syncthreads();
      }
    }
#pragma unroll
  for (int i = 0; i < 4; ++i) {
    int co = co_base + co4 + i;
    float bv = bias[co];
    float4 r = make_float4(acc[0][i] + bv, acc[1][i] + bv, acc[2][i] + bv, acc[3][i] + bv);
    *(float4*)&out[(size_t)(b * CO + co) * HWout + sp_base + sp4] = r;
  }
}

// ---------------- L10 via MFMA ----------------
__global__ __launch_bounds__(256) void deconv_mfma(const __hip_bfloat16* __restrict__ xt,
                                                   const __hip_bfloat16* __restrict__ wb,
                                                   const float* __restrict__ bias, float* __restrict__ out) {
  const int tid = threadIdx.x;
  const int wv = tid >> 6, lane = tid & 63;
  const int ln = lane & 15, kg = lane >> 4;
  const int posb = blockIdx.x * 256 + wv * 64;
  const int sect = posb >> 12;
  const int b = sect >> 2, ph = (sect >> 1) & 1, pw = sect & 1;
  const int a = (posb >> 6) & 63;
  int khs[2], dhs[2], kws[2], dws[2];
  if (ph == 0) { khs[0]=1; dhs[0]=0; khs[1]=3; dhs[1]=-1; }
  else         { khs[0]=0; dhs[0]=1; khs[1]=2; dhs[1]=0; }
  if (pw == 0) { kws[0]=1; dws[0]=0; kws[1]=3; dws[1]=-1; }
  else         { kws[0]=0; dws[0]=1; kws[1]=2; dws[1]=0; }
  f32x4 acc[4] = {{0,0,0,0},{0,0,0,0},{0,0,0,0},{0,0,0,0}};
  const size_t actb = (size_t)b << 12;
#pragma unroll
  for (int ti = 0; ti < 2; ++ti) {
    int ih = a + dhs[ti];
    if ((unsigned)ih >= 64u) continue;
#pragma unroll
    for (int tj = 0; tj < 2; ++tj) {
      const int t = khs[ti] * 4 + kws[tj];
      const int dw = dws[tj];
      const __hip_bfloat16* xrow = xt + ((actb + (ih << 6)) << 8);
#pragma unroll
      for (int c32 = 0; c32 < 8; ++c32) {
        bf16x8 bf = *(const bf16x8*)(wb + ((((size_t)t * 32 + (c32 << 2) + kg) * 16 + ln) << 3));
#pragma unroll
        for (int mf = 0; mf < 4; ++mf) {
          int c = (mf << 4) + ln;
          int iw = c + dw;
          bf16x8 av = {};
          if ((unsigned)iw < 64u)
            av = *(const bf16x8*)(xrow + ((size_t)iw << 8) + (c32 << 5) + (kg << 3));
          acc[mf] = __builtin_amdgcn_mfma_f32_16x16x32_bf16(av, bf, acc[mf], 0, 0, 0);
        }
      }
    }
  }
  if (ln < 3) {
    float bv = bias[ln];
    int oh = 2 * a + ph;
    size_t ob = ((size_t)(b * 3 + ln) << 14) + (oh << 7) + pw;
#pragma unroll
    for (int mf = 0; mf < 4; ++mf)
#pragma unroll
      for (int r = 0; r < 4; ++r) {
        int c = (mf << 4) + (kg << 2) + r;
        out[ob + (c << 1)] = 1.f / (1.f + __expf(-(acc[mf][r] + bv)));
      }
  }
}

// ---------------- VQ: exact f64 (round-13-verified), 256 blocks x 128 threads ----------------
__global__ __launch_bounds__(128) void vq_argmin(const float* __restrict__ enc, const float* __restrict__ emb,
                                                 const double* __restrict__ norms, int* __restrict__ cidx,
                                                 float* __restrict__ closest_out) {
  __shared__ float se[128 * 64];
  int tid = threadIdx.x;
  int r = blockIdx.x * 128 + tid;
  double ef[64];
  const float4* ep = (const float4*)(enc + ((size_t)r << 6));
#pragma unroll
  for (int q = 0; q < 16; ++q) {
    float4 v = ep[q];
    ef[4*q] = v.x; ef[4*q+1] = v.y; ef[4*q+2] = v.z; ef[4*q+3] = v.w;
  }
  double best = 1e300; int bi = 0;
  for (int q = 0; q < 4; ++q) {
    __syncthreads();
    for (int i = tid; i < 8192; i += 128) se[i] = emb[q * 8192 + i];
    __syncthreads();
    for (int k = 0; k < 128; ++k) {
      const float* cp = &se[k << 6];
      double p0 = 0.0, p1 = 0.0, p2 = 0.0, p3 = 0.0;
#pragma unroll
      for (int d = 0; d < 64; d += 4) {
        p0 = fma(ef[d],     (double)cp[d],     p0);
        p1 = fma(ef[d + 1], (double)cp[d + 1], p1);
        p2 = fma(ef[d + 2], (double)cp[d + 2], p2);
        p3 = fma(ef[d + 3], (double)cp[d + 3], p3);
      }
      double dot = (p0 + p1) + (p2 + p3);
      double d2 = norms[q * 128 + k] - 2.0 * dot;
      if (d2 < best) { best = d2; bi = q * 128 + k; }
    }
  }
  cidx[r] = bi;
  closest_out[r] = (float)bi;
}

__global__ __launch_bounds__(256) void vq_gather(const float* __restrict__ enc, const float* __restrict__ emb,
                                                 const int* __restrict__ cidx, __hip_bfloat16* __restrict__ qot,
                                                 float* __restrict__ part) {
  int tid = threadIdx.x;
  int i = blockIdx.x * 256 + tid;
  int r = i >> 6, d = i & 63;
  int k = cidx[r];
  float q = emb[(k << 6) + d];
  float e = enc[i];
  int b = r >> 10;
  int f = ((r & 1023) << 6) + d;
  int d_orig = f >> 10, p = f & 1023;
  qot[(((size_t)(b << 10)) + p) * 64 + d_orig] = __float2bfloat16(q);
  float df = q - e;
  __shared__ float red[256];
  red[tid] = df * df;
  __syncthreads();
  for (int st = 128; st > 0; st >>= 1) {
    if (tid < st) red[tid] += red[tid + st];
    __syncthreads();
  }
  if (tid == 0) part[blockIdx.x] = red[0];
}

__global__ __launch_bounds__(256) void qloss_final(const float* __restrict__ part, float* __restrict__ out) {
  int tid = threadIdx.x;
  double s = 0.0;
  for (int i = tid; i < 8192; i += 256) s += part[i];
  __shared__ double red[256];
  red[tid] = s;
  __syncthreads();
  for (int st = 128; st > 0; st >>= 1) {
    if (tid < st) red[tid] += red[tid + st];
    __syncthreads();
  }
  if (tid == 0) {
    double mean = red[0] / 2097152.0;
    out[0] = (float)(1.25 * mean);
  }
}

// ---------------- host ----------------
extern "C" void kernel_launch(void* const* d_in, const int* in_sizes, int n_in,
                              void* d_out, int out_size, void* d_ws, size_t ws_size,
                              hipStream_t stream) {
  const float* x     = (const float*)d_in[0];
  const float* emb   = (const float*)d_in[1];
  const float* e_w1  = (const float*)d_in[2];
  const float* e_b1  = (const float*)d_in[3];
  const float* e_g1  = (const float*)d_in[4];
  const float* e_be1 = (const float*)d_in[5];
  const float* e_w2  = (const float*)d_in[6];
  const float* e_b2  = (const float*)d_in[7];
  const float* e_g2  = (const float*)d_in[8];
  const float* e_be2 = (const float*)d_in[9];
  const float* e_rw1 = (const float*)d_in[10];
  const float* e_rb1 = (const float*)d_in[11];
  const float* e_rg1 = (const float*)d_in[12];
  const float* e_rbe1= (const float*)d_in[13];
  const float* e_rw2 = (const float*)d_in[14];
  const float* e_rb2 = (const float*)d_in[15];
  const float* e_rg2 = (const float*)d_in[16];
  const float* e_rbe2= (const float*)d_in[17];
  const float* e_pw  = (const float*)d_in[18];
  const float* e_pb  = (const float*)d_in[19];
  const float* d_pw  = (const float*)d_in[20];
  const float* d_pb  = (const float*)d_in[21];
  const float* d_rw1 = (const float*)d_in[22];
  const float* d_rb1 = (const float*)d_in[23];
  const float* d_rg1 = (const float*)d_in[24];
  const float* d_rbe1= (const float*)d_in[25];
  const float* d_rw2 = (const float*)d_in[26];
  const float* d_rb2 = (const float*)d_in[27];
  const float* d_rg2 = (const float*)d_in[28];
  const float* d_rbe2= (const float*)d_in[29];
  const float* d_tw1 = (const float*)d_in[30];
  const float* d_tb1 = (const float*)d_in[31];
  const float* d_tg1 = (const float*)d_in[32];
  const float* d_tbe1= (const float*)d_in[33];
  const float* d_tw2 = (const float*)d_in[34];
  const float* d_tb2 = (const float*)d_in[35];

  float* ws   = (float*)d_ws;
  float* BIG  = ws + OFF_BIG;
  float* BP   = ws + OFF_BP;
  float* ENC  = ws + OFF_ENC;
  float* S    = ws + OFF_S;
  float* W2T  = ws + OFF_W2T;
  float* RW1T = ws + OFF_RW1T;
  float* RW2T = ws + OFF_RW2T;
  float* PWT  = ws + OFF_PWT;
  float* STATS= ws + OFF_STATS;
  double* NORM= (double*)(ws + OFF_NORM);
  int*   CIDX = (int*)(ws + OFF_CIDX);
  float* PART = ws + OFF_PART;
  float* STAT2= ws + OFF_STAT2;
  double* PARTD = (double*)(ws + OFF_STAT2);
  __hip_bfloat16* HT1  = (__hip_bfloat16*)(ws + OFF_HT1);
  __hip_bfloat16* HT2  = (__hip_bfloat16*)(ws + OFF_HT2);
  __hip_bfloat16* HT3  = (__hip_bfloat16*)(ws + OFF_HT3);
  __hip_bfloat16* QOT  = (__hip_bfloat16*)(ws + OFF_QOT);
  __hip_bfloat16* T9BT = (__hip_bfloat16*)(ws + OFF_BIG);
  __hip_bfloat16* DPWB = (__hip_bfloat16*)(ws + OFF_DPWB);
  __hip_bfloat16* DRW1B= (__hip_bfloat16*)(ws + OFF_DRW1B);
  __hip_bfloat16* DRW2B= (__hip_bfloat16*)(ws + OFF_DRW2B);
  __hip_bfloat16* TW1B = (__hip_bfloat16*)(ws + OFF_TW1B);
  __hip_bfloat16* WB   = (__hip_bfloat16*)(ws + OFF_WB);
  float* outp = (float*)d_out;

  dim3 blk(256);
  dim3 bn_grid(256, 8);

  prep_all<<<15746, blk, 0, stream>>>(e_w2, W2T, e_rw1, RW1T, e_rw2, RW2T, e_pw, PWT,
                                      d_tw2, WB, d_pw, DPWB, d_rw1, DRW1B, d_rw2, DRW2B,
                                      d_tw1, TW1B, emb, NORM);

  // ---- encoder (fp32) ----
  conv1_w<<<dim3(16, 32, 2), blk, 0, stream>>>(x, e_w1, e_b1, BIG);
  bn_stats_p<<<bn_grid, blk, 0, stream>>>(BIG, PARTD, 12, 32);
  bn_stats_f<<<1, blk, 0, stream>>>(PARTD, STATS, 131072);
  bn_apply<<<32768, blk, 0, stream>>>((float4*)BIG, nullptr, (float4*)BIG, STATS, e_g1, e_be1, 12, 8388608);
  conv_b64<2, 4><<<dim3(16, 2, 32), blk, 0, stream>>>(BIG, W2T, e_b2, S, 256, 256, 64, 64, 1);
  bn_stats_p<<<bn_grid, blk, 0, stream>>>(S, PARTD, 10, 32);
  bn_stats_f<<<1, blk, 0, stream>>>(PARTD, STATS, 32768);
  bn_apply<<<8192, blk, 0, stream>>>((float4*)S, nullptr, (float4*)S, STATS, e_g2, e_be2, 10, 2097152);
  conv_b64<1, 3><<<dim3(16, 2, 32), blk, 0, stream>>>(S, RW1T, e_rb1, BP, 256, 256, 32, 32, 1);
  bn_stats_p<<<bn_grid, blk, 0, stream>>>(BP, PARTD, 10, 32);
  bn_stats_f<<<1, blk, 0, stream>>>(PARTD, STATS, 32768);
  bn_apply<<<8192, blk, 0, stream>>>((float4*)BP, (float4*)S, (float4*)BP, STATS, e_rg1, e_rbe1, 10, 2097152);
  conv_b64<1, 1><<<dim3(16, 2, 32), blk, 0, stream>>>(BP, RW2T, e_rb2, S, 256, 256, 32, 32, 0);
  bn_stats_p<<<bn_grid, blk, 0, stream>>>(S, PARTD, 10, 32);
  bn_stats_f<<<1, blk, 0, stream>>>(PARTD, STATS, 32768);
  bn_apply<<<8192, blk, 0, stream>>>((float4*)S, (float4*)BP, (float4*)S, STATS, e_rg2, e_rbe2, 10, 2097152);
  conv_tiled<<<dim3(16, 1, 32), blk, 0, stream>>>(S, PWT, e_pb, ENC, 256, 64, 32, 32, 32, 32, 1, 1, 1, 0);

  // ---- VQ ----
  vq_argmin<<<256, dim3(128), 0, stream>>>(ENC, emb, NORM, CIDX, outp + OUT_CLOSEST);
  vq_gather<<<8192, blk, 0, stream>>>(ENC, emb, CIDX, QOT, PART);
  qloss_final<<<1, blk, 0, stream>>>(PART, outp + OUT_QLOSS);

  // ---- decoder (bf16 MFMA) ----
  mconv<64, 1, 1, 0><<<dim3(16, 4, 32), blk, 0, stream>>>(QOT, DPWB, d_pb, S, 256);
  fp32_to_bt<<<4096, blk, 0, stream>>>(S, HT1);
  mconv_s<<<dim3(16, 4, 32), blk, 0, stream>>>(HT1, DRW1B, d_rb1, BP);
  bn_stats_p<<<bn_grid, blk, 0, stream>>>(BP, PARTD, 10, 32);
  bn_stats_f<<<1, blk, 0, stream>>>(PARTD, STATS, 32768);
  bn_apply_td<<<4096, blk, 0, stream>>>(BP, S, S, HT2, STATS, d_rg1, d_rbe1);
  mconv_s<<<dim3(16, 4, 32), blk, 0, stream>>>(HT2, DRW2B, d_rb2, BP);
  bn_stats_p<<<bn_grid, blk, 0, stream>>>(BP, PARTD, 10, 32);
  bn_stats_f<<<1, blk, 0, stream>>>(PARTD, STATS, 32768);
  bn_apply_td<<<4096, blk, 0, stream>>>(BP, S, nullptr, HT3, STATS, d_rg2, d_rbe2);
  mdeconv_s<<<dim3(16, 4, 32), blk, 0, stream>>>(HT3, TW1B, d_tb1, T9BT);
  bnbt_stage1<<<64, blk, 0, stream>>>(T9BT, STAT2);
  bnbt_stage2<<<1, blk, 0, stream>>>(STAT2, STATS);
  bn_apply_bt<<<16384, blk, 0, stream>>>(T9BT, STATS, d_tg1, d_tbe1);
  deconv_mfma<<<2048, blk, 0, stream>>>(T9BT, WB, d_tb2, outp);
}